// Round 2
// baseline (1157.625 us; speedup 1.0000x reference)
//
#include <hip/hip_runtime.h>
#include <hip/hip_bf16.h>

typedef __hip_bfloat16 bf16;

#define FDIM 128
#define SELF_W 2.0f
#define NGRAPH 64

__device__ __forceinline__ float b2f(bf16 v){ return __bfloat162float(v); }

// monotone float -> unsigned encoding for atomicMax on floats
__device__ __forceinline__ unsigned fenc(float f){
  unsigned b = __float_as_uint(f);
  return (b & 0x80000000u) ? ~b : (b | 0x80000000u);
}
__device__ __forceinline__ float fdec(unsigned u){
  unsigned b = (u & 0x80000000u) ? (u ^ 0x80000000u) : ~u;
  return __uint_as_float(b);
}

// ---- input-format probe: flags[0]=floats are f32, flags[1]=ints are int64 ----
__global__ __launch_bounds__(256) void k_probe(const unsigned short* __restrict__ x16,
                                               const int* __restrict__ ei32,
                                               int* __restrict__ flags){
  __shared__ int cbig, codd;
  int tid = threadIdx.x;
  if (tid == 0){ cbig = 0; codd = 0; }
  __syncthreads();
  // bf16 view of x: N(0,1) data -> |v| small. f32 data -> low halves have random
  // exponent fields -> |v|>=2^7 (or NaN/Inf) for ~half of even positions.
  for (int i = tid; i < 4096; i += 256){
    int e = (x16[i] >> 7) & 0xFF;
    if (e >= 134) atomicAdd(&cbig, 1);
  }
  // int64 indices: hi 32-bit words (odd int32 positions) are all zero.
  for (int i = tid; i < 512; i += 256){
    if (ei32[2*i + 1] != 0) atomicAdd(&codd, 1);
  }
  __syncthreads();
  if (tid == 0){
    flags[0] = (cbig >= 64) ? 1 : 0;   // 1 -> floats are f32
    flags[1] = (codd < 8)  ? 1 : 0;    // 1 -> ints are int64
  }
}

// flag-aware float conversion: src (bf16 or f32) -> f32
__global__ void k_cvtf(const void* __restrict__ src, float* __restrict__ dst,
                       int n, const int* __restrict__ flags){
  int i = blockIdx.x*blockDim.x + threadIdx.x;
  if (i >= n) return;
  if (flags[0]) dst[i] = ((const float*)src)[i];
  else          dst[i] = b2f(((const bf16*)src)[i]);
}

// flag-aware int conversion: src (+offset elements) (int32 or int64) -> int32
__global__ void k_cvti(const void* __restrict__ src, int* __restrict__ dst,
                       int n, long long offsetElems, const int* __restrict__ flags){
  int i = blockIdx.x*blockDim.x + threadIdx.x;
  if (i >= n) return;
  if (flags[1]) dst[i] = (int)(((const long long*)src)[offsetElems + i]);
  else          dst[i] = ((const int*)src)[offsetElems + i];
}

__global__ void k_init(float* deg, unsigned* cnt, int N){
  int i = blockIdx.x*blockDim.x + threadIdx.x;
  if (i < N){ deg[i] = SELF_W; cnt[i] = 0u; }
}

__global__ void k_fill_edges(int* esrc, float* ecoef, int E){
  int i = blockIdx.x*blockDim.x + threadIdx.x;
  if (i < E){ esrc[i] = 0; ecoef[i] = 0.f; }
}

__global__ void k_deg(const int* __restrict__ dst, const float* __restrict__ ew,
                      float* __restrict__ deg, unsigned* __restrict__ cnt, int E, int N){
  int e = blockIdx.x*blockDim.x + threadIdx.x;
  if (e < E){
    int d = dst[e];
    if ((unsigned)d < (unsigned)N){
      atomicAdd(&deg[d], ew[e]);
      atomicAdd(&cnt[d], 1u);
    }
  }
}

__global__ void k_dinv(float* deg, int N){
  int i = blockIdx.x*blockDim.x + threadIdx.x;
  if (i < N){ float d = deg[i]; deg[i] = (d > 0.f) ? rsqrtf(d) : 0.f; }
}

// single-block exclusive scan of cnt -> off; resets cnt to 0 (reused as cursor)
__global__ __launch_bounds__(1024) void k_scan(unsigned* __restrict__ cnt,
                                               unsigned* __restrict__ off, int N){
  __shared__ unsigned s[1024];
  int tid = threadIdx.x;
  unsigned running = 0u;
  for (int base = 0; base < N; base += 1024){
    int i = base + tid;
    unsigned v = (i < N) ? cnt[i] : 0u;
    if (i < N) cnt[i] = 0u;
    s[tid] = v;
    __syncthreads();
    for (int d = 1; d < 1024; d <<= 1){
      unsigned tv = (tid >= d) ? s[tid - d] : 0u;
      __syncthreads();
      s[tid] += tv;
      __syncthreads();
    }
    if (i < N) off[i] = running + s[tid] - v;
    unsigned tot = s[1023];
    __syncthreads();
    running += tot;
  }
  if (tid == 0) off[N] = running;
}

__global__ void k_bucket(const int* __restrict__ src, const int* __restrict__ dst,
                         const float* __restrict__ ew, const float* __restrict__ dinv,
                         const unsigned* __restrict__ off, unsigned* __restrict__ cur,
                         int* __restrict__ esrc, float* __restrict__ ecoef, int E, int N){
  int e = blockIdx.x*blockDim.x + threadIdx.x;
  if (e < E){
    int s_ = src[e], d = dst[e];
    if ((unsigned)s_ >= (unsigned)N || (unsigned)d >= (unsigned)N) return;
    unsigned pos = off[d] + atomicAdd(&cur[d], 1u);
    if (pos < (unsigned)E){
      esrc[pos]  = s_;
      ecoef[pos] = dinv[s_] * ew[e] * dinv[d];
    }
  }
}

// t[N,128] = in[N,128] @ W[128,128]; f32. A 64-row tile in LDS (transposed, +pad),
// W streamed from L1/L2. 256 thr: 4 rows x 8 cols each.
__global__ __launch_bounds__(256) void k_gemm(const float* __restrict__ in,
                                              const float* __restrict__ W,
                                              float* __restrict__ out, int N){
  __shared__ float shA[128*68];
  int t = threadIdx.x;
  int row0 = blockIdx.x * 64;
  #pragma unroll
  for (int i = 0; i < 32; i++){
    int e = t + 256*i;         // 8192 = 64 rows * 128 k
    int r = e >> 7, k = e & 127;
    int row = row0 + r;
    float v = (row < N) ? in[(size_t)row*FDIM + k] : 0.f;
    shA[k*68 + r] = v;
  }
  __syncthreads();

  int tcg = t & 15, trg = t >> 4;
  int r0 = trg * 4, j0 = tcg * 8;
  float acc[4][8];
  #pragma unroll
  for (int a_ = 0; a_ < 4; a_++)
    #pragma unroll
    for (int b_ = 0; b_ < 8; b_++) acc[a_][b_] = 0.f;

  #pragma unroll 4
  for (int k = 0; k < FDIM; k++){
    const float4 a  = *(const float4*)&shA[k*68 + r0];
    const float4* wr = (const float4*)(W + (size_t)k*FDIM + j0);
    const float4 w0 = wr[0];
    const float4 w1 = wr[1];
    const float av[4] = {a.x, a.y, a.z, a.w};
    const float wv[8] = {w0.x,w0.y,w0.z,w0.w, w1.x,w1.y,w1.z,w1.w};
    #pragma unroll
    for (int rr = 0; rr < 4; rr++)
      #pragma unroll
      for (int cc = 0; cc < 8; cc++)
        acc[rr][cc] += av[rr] * wv[cc];
  }

  #pragma unroll
  for (int rr = 0; rr < 4; rr++){
    int row = row0 + r0 + rr;
    if (row < N){
      float* po = out + (size_t)row*FDIM + j0;
      *(float4*)(po)     = make_float4(acc[rr][0], acc[rr][1], acc[rr][2], acc[rr][3]);
      *(float4*)(po + 4) = make_float4(acc[rr][4], acc[rr][5], acc[rr][6], acc[rr][7]);
    }
  }
}

// one wave64 per node; lane owns 2 columns. CSR gather, fused bias+tanh.
__global__ __launch_bounds__(256) void k_agg(const float* __restrict__ t,
                                             const float* __restrict__ dinv,
                                             const unsigned* __restrict__ off,
                                             const int* __restrict__ esrc,
                                             const float* __restrict__ ecoef,
                                             const float* __restrict__ bias,
                                             float* __restrict__ hout, int N, int E){
  int n    = (int)((blockIdx.x*blockDim.x + threadIdx.x) >> 6);
  int lane = threadIdx.x & 63;
  if (n >= N) return;
  float di = dinv[n];
  float sw = di * di * SELF_W;
  float2 v = ((const float2*)(t + (size_t)n*FDIM))[lane];
  float a0 = sw * v.x, a1 = sw * v.y;
  unsigned beg = off[n], end = off[n+1];
  if (end > (unsigned)E) end = (unsigned)E;
  if (beg > end) beg = end;
  for (unsigned i = beg; i < end; i++){
    int s_  = esrc[i];
    float cf = ecoef[i];
    float2 tv = ((const float2*)(t + (size_t)s_*FDIM))[lane];
    a0 += cf * tv.x;
    a1 += cf * tv.y;
  }
  int c = lane * 2;
  a0 = tanhf(a0 + bias[c]);
  a1 = tanhf(a1 + bias[c+1]);
  ((float2*)(hout + (size_t)n*FDIM))[lane] = make_float2(a0, a1);
}

__global__ void k_pool_init(unsigned* gmaxu, float* gsum, unsigned* gcnt){
  int i = blockIdx.x*blockDim.x + threadIdx.x;
  if (i < NGRAPH*FDIM){ gmaxu[i] = 0u; gsum[i] = 0.f; }
  if (i < NGRAPH) gcnt[i] = 0u;
}

__global__ __launch_bounds__(256) void k_pool(const float* __restrict__ h,
                                              const int* __restrict__ batch,
                                              unsigned* __restrict__ gmaxu,
                                              float* __restrict__ gsum,
                                              unsigned* __restrict__ gcnt, int N){
  int n    = (int)((blockIdx.x*blockDim.x + threadIdx.x) >> 6);
  int lane = threadIdx.x & 63;
  if (n >= N) return;
  int g = batch[n];
  if ((unsigned)g >= (unsigned)NGRAPH) return;
  float2 v = ((const float2*)(h + (size_t)n*FDIM))[lane];
  int c = lane * 2;
  atomicMax(&gmaxu[g*FDIM + c],     fenc(v.x));
  atomicMax(&gmaxu[g*FDIM + c + 1], fenc(v.y));
  atomicAdd(&gsum[g*FDIM + c],     v.x);
  atomicAdd(&gsum[g*FDIM + c + 1], v.y);
  if (lane == 0) atomicAdd(&gcnt[g], 1u);
}

// 64 blocks x 256 thr: hidden = [gmax | gmean], out = hidden @ Wout + bout.
// Writes bf16 or f32 per flags[0].
__global__ __launch_bounds__(256) void k_out(const unsigned* __restrict__ gmaxu,
                                             const float* __restrict__ gsum,
                                             const unsigned* __restrict__ gcnt,
                                             const float* __restrict__ Wout,
                                             const float* __restrict__ bout,
                                             void* __restrict__ outp,
                                             const int* __restrict__ flags){
  int g = blockIdx.x;
  int c = threadIdx.x;
  unsigned nc = gcnt[g];
  float val;
  if (c < FDIM){
    val = nc ? fdec(gmaxu[g*FDIM + c]) : 0.f;   // empty-graph guard
  } else {
    float denom = nc ? (float)nc : 1.f;
    val = gsum[g*FDIM + (c - FDIM)] / denom;
  }
  int f32out = flags[0];
  int hidx = NGRAPH + g*(2*FDIM) + c;
  if (f32out) ((float*)outp)[hidx] = val;
  else        ((bf16*)outp)[hidx] = __float2bfloat16(val);

  __shared__ float red[256];
  red[c] = val * Wout[c];
  __syncthreads();
  for (int s = 128; s > 0; s >>= 1){
    if (c < s) red[c] += red[c + s];
    __syncthreads();
  }
  if (c == 0){
    float o = red[0] + bout[0];
    if (f32out) ((float*)outp)[g] = o;
    else        ((bf16*)outp)[g] = __float2bfloat16(o);
  }
}

extern "C" void kernel_launch(void* const* d_in, const int* in_sizes, int n_in,
                              void* d_out, int out_size, void* d_ws, size_t ws_size,
                              hipStream_t stream){
  // Sizes derived ONLY from float arrays (element counts are width-unambiguous):
  int N = in_sizes[0] / FDIM;   // x: [N,128]
  int E = in_sizes[3];          // edge_weight: [E]

  char* p = (char*)d_ws;
  auto alloc = [&](size_t bytes){ char* r = p; p += (bytes + 255) & ~(size_t)255; return r; };
  int*      flags  = (int*)     alloc(16);
  float*    xf     = (float*)   alloc((size_t)N*FDIM*4);
  float*    ewf    = (float*)   alloc((size_t)E*4);
  float*    pf     = (float*)   alloc((size_t)(4*FDIM*FDIM + 4*FDIM + 2*FDIM + 1)*4);
  int*      src32  = (int*)     alloc((size_t)E*4);
  int*      dst32  = (int*)     alloc((size_t)E*4);
  int*      bat32  = (int*)     alloc((size_t)N*4);
  float*    deg    = (float*)   alloc((size_t)N*4);       // becomes dinv in place
  unsigned* cnt    = (unsigned*)alloc((size_t)N*4);
  unsigned* off    = (unsigned*)alloc((size_t)(N+1)*4);
  int*      esrc   = (int*)     alloc((size_t)E*4);
  float*    ecoef  = (float*)   alloc((size_t)E*4);
  float*    buf0   = (float*)   alloc((size_t)N*FDIM*4);
  float*    buf1   = (float*)   alloc((size_t)N*FDIM*4);
  unsigned* gmaxu  = (unsigned*)alloc((size_t)NGRAPH*FDIM*4);
  float*    gsum   = (float*)   alloc((size_t)NGRAPH*FDIM*4);
  unsigned* gcnt   = (unsigned*)alloc((size_t)NGRAPH*4);

  float* Wf[4] = {pf, pf + 16384, pf + 2*16384, pf + 3*16384};
  float* bf_[4] = {pf + 65536, pf + 65536 + 128, pf + 65536 + 256, pf + 65536 + 384};
  float* Woutf = pf + 66048;
  float* boutf = pf + 66304;

  k_probe<<<1, 256, 0, stream>>>((const unsigned short*)d_in[0], (const int*)d_in[1], flags);

  int gNF = (N*FDIM + 255)/256, gE = (E + 255)/256, gN = (N + 255)/256;
  k_cvtf<<<gNF, 256, 0, stream>>>(d_in[0], xf, N*FDIM, flags);
  k_cvtf<<<gE,  256, 0, stream>>>(d_in[3], ewf, E, flags);
  for (int l = 0; l < 4; l++){
    k_cvtf<<<64, 256, 0, stream>>>(d_in[4 + 2*l], Wf[l],  FDIM*FDIM, flags);
    k_cvtf<<<1,  128, 0, stream>>>(d_in[5 + 2*l], bf_[l], FDIM, flags);
  }
  k_cvtf<<<1, 256, 0, stream>>>(d_in[12], Woutf, 2*FDIM, flags);
  k_cvtf<<<1, 64,  0, stream>>>(d_in[13], boutf, 1, flags);
  k_cvti<<<gE, 256, 0, stream>>>(d_in[1], src32, E, 0, flags);
  k_cvti<<<gE, 256, 0, stream>>>(d_in[1], dst32, E, (long long)E, flags);
  k_cvti<<<gN, 256, 0, stream>>>(d_in[2], bat32, N, 0, flags);

  k_init<<<gN, 256, 0, stream>>>(deg, cnt, N);
  k_fill_edges<<<gE, 256, 0, stream>>>(esrc, ecoef, E);
  k_deg <<<gE, 256, 0, stream>>>(dst32, ewf, deg, cnt, E, N);
  k_dinv<<<gN, 256, 0, stream>>>(deg, N);
  k_scan<<<1, 1024, 0, stream>>>(cnt, off, N);
  k_bucket<<<gE, 256, 0, stream>>>(src32, dst32, ewf, deg, off, cnt, esrc, ecoef, E, N);

  int gG = (N + 63)/64;       // gemm blocks
  int gA = (N + 3)/4;         // 1 wave per node, 4 waves/block

  k_gemm<<<gG, 256, 0, stream>>>(xf, Wf[0], buf0, N);
  k_agg<<<gA, 256, 0, stream>>>(buf0, deg, off, esrc, ecoef, bf_[0], buf1, N, E);
  for (int l = 1; l < 4; l++){
    k_gemm<<<gG, 256, 0, stream>>>(buf1, Wf[l], buf0, N);
    k_agg<<<gA, 256, 0, stream>>>(buf0, deg, off, esrc, ecoef, bf_[l], buf1, N, E);
  }

  k_pool_init<<<(NGRAPH*FDIM + 255)/256, 256, 0, stream>>>(gmaxu, gsum, gcnt);
  k_pool<<<gA, 256, 0, stream>>>(buf1, bat32, gmaxu, gsum, gcnt, N);
  k_out<<<NGRAPH, 256, 0, stream>>>(gmaxu, gsum, gcnt, Woutf, boutf, d_out, flags);
}

// Round 3
// 749.693 us; speedup vs baseline: 1.5441x; 1.5441x over previous
//
#include <hip/hip_runtime.h>
#include <hip/hip_bf16.h>

typedef __hip_bfloat16 bf16;

#define FDIM 128
#define SELF_W 2.0f
#define NGRAPH 64

__device__ __forceinline__ float b2f(bf16 v){ return __bfloat162float(v); }

// monotone float -> unsigned encoding for atomicMax on floats
__device__ __forceinline__ unsigned fenc(float f){
  unsigned b = __float_as_uint(f);
  return (b & 0x80000000u) ? ~b : (b | 0x80000000u);
}
__device__ __forceinline__ float fdec(unsigned u){
  unsigned b = (u & 0x80000000u) ? (u ^ 0x80000000u) : ~u;
  return __uint_as_float(b);
}

// ---- input-format probe: flags[0]=floats are f32, flags[1]=ints are int64 ----
__global__ __launch_bounds__(256) void k_probe(const unsigned short* __restrict__ x16,
                                               const int* __restrict__ ei32,
                                               int* __restrict__ flags){
  __shared__ int cbig, codd;
  int tid = threadIdx.x;
  if (tid == 0){ cbig = 0; codd = 0; }
  __syncthreads();
  for (int i = tid; i < 4096; i += 256){
    int e = (x16[i] >> 7) & 0xFF;
    if (e >= 134) atomicAdd(&cbig, 1);
  }
  for (int i = tid; i < 512; i += 256){
    if (ei32[2*i + 1] != 0) atomicAdd(&codd, 1);
  }
  __syncthreads();
  if (tid == 0){
    flags[0] = (cbig >= 64) ? 1 : 0;   // 1 -> floats are f32
    flags[1] = (codd < 8)  ? 1 : 0;    // 1 -> ints are int64
  }
}

// flag-aware float conversion (x only)
__global__ void k_cvtf(const void* __restrict__ src, float* __restrict__ dst,
                       int n, const int* __restrict__ flags){
  int i = blockIdx.x*blockDim.x + threadIdx.x;
  if (i >= n) return;
  if (flags[0]) dst[i] = ((const float*)src)[i];
  else          dst[i] = b2f(((const bf16*)src)[i]);
}

// all 10 parameter tensors -> pf in one launch
struct PtrPack { const void* p[10]; };
__global__ void k_cvt_params(PtrPack pk, float* __restrict__ pf,
                             const int* __restrict__ flags){
  const int sz[10]  = {16384,16384,16384,16384,128,128,128,128,256,1};
  const int dst[10] = {0,16384,32768,49152,65536,65664,65792,65920,66048,66304};
  int i = blockIdx.x*blockDim.x + threadIdx.x;
  if (i >= 66305) return;
  int seg = 0, rem = i;
  while (rem >= sz[seg]){ rem -= sz[seg]; seg++; }
  float v = flags[0] ? ((const float*)pk.p[seg])[rem]
                     : b2f(((const bf16*)pk.p[seg])[rem]);
  pf[dst[seg] + rem] = v;
}

// node-side setup: deg=SELF_W, cnt=0, batch -> int32
__global__ void k_node_setup(const void* __restrict__ bat_src, int* __restrict__ bat32,
                             float* __restrict__ deg, unsigned* __restrict__ cnt,
                             int N, const int* __restrict__ flags){
  int i = blockIdx.x*blockDim.x + threadIdx.x;
  if (i >= N) return;
  deg[i] = SELF_W; cnt[i] = 0u;
  bat32[i] = flags[1] ? (int)(((const long long*)bat_src)[i])
                      : ((const int*)bat_src)[i];
}

// edge-side setup: src/dst -> int32, ew -> f32, esrc/ecoef prefill
__global__ void k_edge_setup(const void* __restrict__ ei, const void* __restrict__ ew,
                             int* __restrict__ src32, int* __restrict__ dst32,
                             float* __restrict__ ewf, int* __restrict__ esrc,
                             float* __restrict__ ecoef, int E,
                             const int* __restrict__ flags){
  int e = blockIdx.x*blockDim.x + threadIdx.x;
  if (e >= E) return;
  if (flags[1]){
    src32[e] = (int)(((const long long*)ei)[e]);
    dst32[e] = (int)(((const long long*)ei)[(long long)E + e]);
  } else {
    src32[e] = ((const int*)ei)[e];
    dst32[e] = ((const int*)ei)[(long long)E + e];
  }
  ewf[e] = flags[0] ? ((const float*)ew)[e] : b2f(((const bf16*)ew)[e]);
  esrc[e] = 0; ecoef[e] = 0.f;
}

__global__ void k_deg(const int* __restrict__ dst, const float* __restrict__ ew,
                      float* __restrict__ deg, unsigned* __restrict__ cnt, int E, int N){
  int e = blockIdx.x*blockDim.x + threadIdx.x;
  if (e < E){
    int d = dst[e];
    if ((unsigned)d < (unsigned)N){
      atomicAdd(&deg[d], ew[e]);
      atomicAdd(&cnt[d], 1u);
    }
  }
}

__global__ void k_dinv(float* deg, int N){
  int i = blockIdx.x*blockDim.x + threadIdx.x;
  if (i < N){ float d = deg[i]; deg[i] = (d > 0.f) ? rsqrtf(d) : 0.f; }
}

__device__ __forceinline__ unsigned wave_incl_scan(unsigned v){
  int lane = threadIdx.x & 63;
  #pragma unroll
  for (int d = 1; d < 64; d <<= 1){
    unsigned t = __shfl_up(v, d, 64);
    if (lane >= d) v += t;
  }
  return v;
}

// single-block exclusive scan of cnt -> off (shfl-based; resets cnt to 0)
__global__ __launch_bounds__(1024) void k_scan(unsigned* __restrict__ cnt,
                                               unsigned* __restrict__ off, int N){
  __shared__ unsigned wsum[16];
  __shared__ unsigned chunk_tot;
  int tid = threadIdx.x, lane = tid & 63, wid = tid >> 6;
  unsigned running = 0u;
  for (int base = 0; base < N; base += 4096){
    int i0 = base + tid*4;
    unsigned v0=0u,v1=0u,v2=0u,v3=0u;
    if (i0+0 < N){ v0 = cnt[i0+0]; cnt[i0+0] = 0u; }
    if (i0+1 < N){ v1 = cnt[i0+1]; cnt[i0+1] = 0u; }
    if (i0+2 < N){ v2 = cnt[i0+2]; cnt[i0+2] = 0u; }
    if (i0+3 < N){ v3 = cnt[i0+3]; cnt[i0+3] = 0u; }
    unsigned tsum = v0+v1+v2+v3;
    unsigned isc = wave_incl_scan(tsum);       // inclusive within wave
    if (lane == 63) wsum[wid] = isc;
    __syncthreads();
    if (wid == 0){
      unsigned w = (lane < 16) ? wsum[lane] : 0u;
      unsigned wsc = wave_incl_scan(w);
      if (lane < 16) wsum[lane] = wsc - w;     // exclusive wave offsets
      if (lane == 15) chunk_tot = wsc;
    }
    __syncthreads();
    unsigned ex = running + wsum[wid] + (isc - tsum);
    if (i0+0 < N) off[i0+0] = ex;
    if (i0+1 < N) off[i0+1] = ex + v0;
    if (i0+2 < N) off[i0+2] = ex + v0 + v1;
    if (i0+3 < N) off[i0+3] = ex + v0 + v1 + v2;
    running += chunk_tot;
    __syncthreads();
  }
  if (tid == 0) off[N] = running;
}

__global__ void k_bucket(const int* __restrict__ src, const int* __restrict__ dst,
                         const float* __restrict__ ew, const float* __restrict__ dinv,
                         const unsigned* __restrict__ off, unsigned* __restrict__ cur,
                         int* __restrict__ esrc, float* __restrict__ ecoef, int E, int N){
  int e = blockIdx.x*blockDim.x + threadIdx.x;
  if (e < E){
    int s_ = src[e], d = dst[e];
    if ((unsigned)s_ >= (unsigned)N || (unsigned)d >= (unsigned)N) return;
    unsigned pos = off[d] + atomicAdd(&cur[d], 1u);
    if (pos < (unsigned)E){
      esrc[pos]  = s_;
      ecoef[pos] = dinv[s_] * ew[e] * dinv[d];
    }
  }
}

// graph segment boundaries via binary search on sorted batch
__global__ void k_bounds(const int* __restrict__ bat, int N,
                         unsigned* __restrict__ start, unsigned* __restrict__ gcnt){
  __shared__ unsigned s[NGRAPH+1];
  int g = threadIdx.x;
  if (g <= NGRAPH){
    int lo = 0, hi = N;
    while (lo < hi){ int mid = (lo + hi) >> 1; if (bat[mid] < g) lo = mid + 1; else hi = mid; }
    s[g] = (unsigned)lo;
  }
  __syncthreads();
  if (g < NGRAPH){ start[g] = s[g]; gcnt[g] = s[g+1] - s[g]; }
  if (g == NGRAPH) start[NGRAPH] = s[NGRAPH];
}

// t[N,128] = in[N,128] @ W[128,128]; f32. 256 thr: 4 rows x 8 cols each.
__global__ __launch_bounds__(256) void k_gemm(const float* __restrict__ in,
                                              const float* __restrict__ W,
                                              float* __restrict__ out, int N){
  __shared__ float shA[128*68];
  int t = threadIdx.x;
  int row0 = blockIdx.x * 64;
  #pragma unroll
  for (int i = 0; i < 32; i++){
    int e = t + 256*i;
    int r = e >> 7, k = e & 127;
    int row = row0 + r;
    float v = (row < N) ? in[(size_t)row*FDIM + k] : 0.f;
    shA[k*68 + r] = v;
  }
  __syncthreads();

  int tcg = t & 15, trg = t >> 4;
  int r0 = trg * 4, j0 = tcg * 8;
  float acc[4][8];
  #pragma unroll
  for (int a_ = 0; a_ < 4; a_++)
    #pragma unroll
    for (int b_ = 0; b_ < 8; b_++) acc[a_][b_] = 0.f;

  #pragma unroll 4
  for (int k = 0; k < FDIM; k++){
    const float4 a  = *(const float4*)&shA[k*68 + r0];
    const float4* wr = (const float4*)(W + (size_t)k*FDIM + j0);
    const float4 w0 = wr[0];
    const float4 w1 = wr[1];
    const float av[4] = {a.x, a.y, a.z, a.w};
    const float wv[8] = {w0.x,w0.y,w0.z,w0.w, w1.x,w1.y,w1.z,w1.w};
    #pragma unroll
    for (int rr = 0; rr < 4; rr++)
      #pragma unroll
      for (int cc = 0; cc < 8; cc++)
        acc[rr][cc] += av[rr] * wv[cc];
  }

  #pragma unroll
  for (int rr = 0; rr < 4; rr++){
    int row = row0 + r0 + rr;
    if (row < N){
      float* po = out + (size_t)row*FDIM + j0;
      *(float4*)(po)     = make_float4(acc[rr][0], acc[rr][1], acc[rr][2], acc[rr][3]);
      *(float4*)(po + 4) = make_float4(acc[rr][4], acc[rr][5], acc[rr][6], acc[rr][7]);
    }
  }
}

// one wave64 per node; lane owns 2 columns. CSR gather, fused bias+tanh.
__global__ __launch_bounds__(256) void k_agg(const float* __restrict__ t,
                                             const float* __restrict__ dinv,
                                             const unsigned* __restrict__ off,
                                             const int* __restrict__ esrc,
                                             const float* __restrict__ ecoef,
                                             const float* __restrict__ bias,
                                             float* __restrict__ hout, int N, int E){
  int n    = (int)((blockIdx.x*blockDim.x + threadIdx.x) >> 6);
  int lane = threadIdx.x & 63;
  if (n >= N) return;
  float di = dinv[n];
  float sw = di * di * SELF_W;
  float2 v = ((const float2*)(t + (size_t)n*FDIM))[lane];
  float a0 = sw * v.x, a1 = sw * v.y;
  unsigned beg = off[n], end = off[n+1];
  if (end > (unsigned)E) end = (unsigned)E;
  if (beg > end) beg = end;
  for (unsigned i = beg; i < end; i++){
    int s_  = esrc[i];
    float cf = ecoef[i];
    float2 tv = ((const float2*)(t + (size_t)s_*FDIM))[lane];
    a0 += cf * tv.x;
    a1 += cf * tv.y;
  }
  int c = lane * 2;
  a0 = tanhf(a0 + bias[c]);
  a1 = tanhf(a1 + bias[c+1]);
  ((float2*)(hout + (size_t)n*FDIM))[lane] = make_float2(a0, a1);
}

__global__ void k_pool_init(unsigned* gmaxu, float* gsum){
  int i = blockIdx.x*blockDim.x + threadIdx.x;
  if (i < NGRAPH*FDIM){ gmaxu[i] = 0u; gsum[i] = 0.f; }
}

// 4 blocks per graph, contiguous node slices, register-local reduce, 1 atomic/col/block
__global__ __launch_bounds__(256) void k_pool2(const float* __restrict__ h,
                                               const unsigned* __restrict__ start,
                                               unsigned* __restrict__ gmaxu,
                                               float* __restrict__ gsum){
  int g = blockIdx.x >> 2, sub = blockIdx.x & 3;
  int col = threadIdx.x & 127, half = threadIdx.x >> 7;
  unsigned s0 = start[g], s1 = start[g+1];
  float m = -INFINITY, sm = 0.f;
  for (unsigned n = s0 + sub*2 + half; n < s1; n += 8){
    float v = h[(size_t)n*FDIM + col];
    m = fmaxf(m, v); sm += v;
  }
  __shared__ float shm[256], shs[256];
  shm[threadIdx.x] = m; shs[threadIdx.x] = sm;
  __syncthreads();
  if (half == 0){
    m = fmaxf(m, shm[threadIdx.x + 128]);
    sm += shs[threadIdx.x + 128];
    if (m > -INFINITY) atomicMax(&gmaxu[g*FDIM + col], fenc(m));
    atomicAdd(&gsum[g*FDIM + col], sm);
  }
}

// 64 blocks x 256 thr: hidden = [gmax | gmean], out = hidden @ Wout + bout
__global__ __launch_bounds__(256) void k_out(const unsigned* __restrict__ gmaxu,
                                             const float* __restrict__ gsum,
                                             const unsigned* __restrict__ gcnt,
                                             const float* __restrict__ Wout,
                                             const float* __restrict__ bout,
                                             void* __restrict__ outp,
                                             const int* __restrict__ flags){
  int g = blockIdx.x;
  int c = threadIdx.x;
  unsigned nc = gcnt[g];
  float val;
  if (c < FDIM){
    val = nc ? fdec(gmaxu[g*FDIM + c]) : 0.f;   // empty-graph guard
  } else {
    float denom = nc ? (float)nc : 1.f;
    val = gsum[g*FDIM + (c - FDIM)] / denom;
  }
  int f32out = flags[0];
  int hidx = NGRAPH + g*(2*FDIM) + c;
  if (f32out) ((float*)outp)[hidx] = val;
  else        ((bf16*)outp)[hidx] = __float2bfloat16(val);

  __shared__ float red[256];
  red[c] = val * Wout[c];
  __syncthreads();
  for (int s = 128; s > 0; s >>= 1){
    if (c < s) red[c] += red[c + s];
    __syncthreads();
  }
  if (c == 0){
    float o = red[0] + bout[0];
    if (f32out) ((float*)outp)[g] = o;
    else        ((bf16*)outp)[g] = __float2bfloat16(o);
  }
}

extern "C" void kernel_launch(void* const* d_in, const int* in_sizes, int n_in,
                              void* d_out, int out_size, void* d_ws, size_t ws_size,
                              hipStream_t stream){
  int N = in_sizes[0] / FDIM;   // x: [N,128]
  int E = in_sizes[3];          // edge_weight: [E]

  char* p = (char*)d_ws;
  auto alloc = [&](size_t bytes){ char* r = p; p += (bytes + 255) & ~(size_t)255; return r; };
  int*      flags  = (int*)     alloc(16);
  float*    xf     = (float*)   alloc((size_t)N*FDIM*4);
  float*    pf     = (float*)   alloc((size_t)(66305 + 64)*4);
  float*    ewf    = (float*)   alloc((size_t)E*4);
  int*      src32  = (int*)     alloc((size_t)E*4);
  int*      dst32  = (int*)     alloc((size_t)E*4);
  int*      bat32  = (int*)     alloc((size_t)N*4);
  float*    deg    = (float*)   alloc((size_t)N*4);       // becomes dinv in place
  unsigned* cnt    = (unsigned*)alloc((size_t)N*4);
  unsigned* off    = (unsigned*)alloc((size_t)(N+1)*4);
  int*      esrc   = (int*)     alloc((size_t)E*4);
  float*    ecoef  = (float*)   alloc((size_t)E*4);
  float*    buf0   = (float*)   alloc((size_t)N*FDIM*4);
  float*    buf1   = (float*)   alloc((size_t)N*FDIM*4);
  unsigned* gmaxu  = (unsigned*)alloc((size_t)NGRAPH*FDIM*4);
  float*    gsum   = (float*)   alloc((size_t)NGRAPH*FDIM*4);
  unsigned* gcnt   = (unsigned*)alloc((size_t)NGRAPH*4);
  unsigned* gstart = (unsigned*)alloc((size_t)(NGRAPH+1)*4);

  float* Wf[4]  = {pf, pf + 16384, pf + 32768, pf + 49152};
  float* bf_[4] = {pf + 65536, pf + 65664, pf + 65792, pf + 65920};
  float* Woutf  = pf + 66048;
  float* boutf  = pf + 66304;

  k_probe<<<1, 256, 0, stream>>>((const unsigned short*)d_in[0], (const int*)d_in[1], flags);

  int gNF = (N*FDIM + 255)/256, gE = (E + 255)/256, gN = (N + 255)/256;
  k_cvtf<<<gNF, 256, 0, stream>>>(d_in[0], xf, N*FDIM, flags);
  PtrPack pk;
  pk.p[0]=d_in[4]; pk.p[1]=d_in[6]; pk.p[2]=d_in[8]; pk.p[3]=d_in[10];
  pk.p[4]=d_in[5]; pk.p[5]=d_in[7]; pk.p[6]=d_in[9]; pk.p[7]=d_in[11];
  pk.p[8]=d_in[12]; pk.p[9]=d_in[13];
  k_cvt_params<<<(66305 + 255)/256, 256, 0, stream>>>(pk, pf, flags);
  k_node_setup<<<gN, 256, 0, stream>>>(d_in[2], bat32, deg, cnt, N, flags);
  k_edge_setup<<<gE, 256, 0, stream>>>(d_in[1], d_in[3], src32, dst32, ewf, esrc, ecoef, E, flags);

  k_deg <<<gE, 256, 0, stream>>>(dst32, ewf, deg, cnt, E, N);
  k_dinv<<<gN, 256, 0, stream>>>(deg, N);
  k_scan<<<1, 1024, 0, stream>>>(cnt, off, N);
  k_bucket<<<gE, 256, 0, stream>>>(src32, dst32, ewf, deg, off, cnt, esrc, ecoef, E, N);
  k_bounds<<<1, 128, 0, stream>>>(bat32, N, gstart, gcnt);

  int gG = (N + 63)/64;
  int gA = (N + 3)/4;

  k_gemm<<<gG, 256, 0, stream>>>(xf, Wf[0], buf0, N);
  k_agg<<<gA, 256, 0, stream>>>(buf0, deg, off, esrc, ecoef, bf_[0], buf1, N, E);
  for (int l = 1; l < 4; l++){
    k_gemm<<<gG, 256, 0, stream>>>(buf1, Wf[l], buf0, N);
    k_agg<<<gA, 256, 0, stream>>>(buf0, deg, off, esrc, ecoef, bf_[l], buf1, N, E);
  }

  k_pool_init<<<(NGRAPH*FDIM + 255)/256, 256, 0, stream>>>(gmaxu, gsum);
  k_pool2<<<4*NGRAPH, 256, 0, stream>>>(buf1, gstart, gmaxu, gsum);
  k_out<<<NGRAPH, 256, 0, stream>>>(gmaxu, gsum, gcnt, Woutf, boutf, d_out, flags);
}

// Round 4
// 588.990 us; speedup vs baseline: 1.9654x; 1.2728x over previous
//
#include <hip/hip_runtime.h>
#include <hip/hip_bf16.h>
#include <hip/hip_fp16.h>

typedef __hip_bfloat16 bf16;

#define FDIM 128
#define SELF_W 2.0f
#define NGRAPH 64

__device__ __forceinline__ float b2f(bf16 v){ return __bfloat162float(v); }

// monotone float -> unsigned encoding for atomicMax on floats
__device__ __forceinline__ unsigned fenc(float f){
  unsigned b = __float_as_uint(f);
  return (b & 0x80000000u) ? ~b : (b | 0x80000000u);
}
__device__ __forceinline__ float fdec(unsigned u){
  unsigned b = (u & 0x80000000u) ? (u ^ 0x80000000u) : ~u;
  return __uint_as_float(b);
}

// flag-aware raw readers
__device__ __forceinline__ float rdf(const void* p, long long i, int f32){
  return f32 ? ((const float*)p)[i] : b2f(((const bf16*)p)[i]);
}
__device__ __forceinline__ int rdi(const void* p, long long i, int i64){
  return i64 ? (int)(((const long long*)p)[i]) : ((const int*)p)[i];
}

// ---- input-format probe: flags[0]=floats are f32, flags[1]=ints are int64 ----
__global__ __launch_bounds__(256) void k_probe(const unsigned short* __restrict__ x16,
                                               const int* __restrict__ ei32,
                                               int* __restrict__ flags){
  __shared__ int cbig, codd;
  int tid = threadIdx.x;
  if (tid == 0){ cbig = 0; codd = 0; }
  __syncthreads();
  for (int i = tid; i < 4096; i += 256){
    int e = (x16[i] >> 7) & 0xFF;
    if (e >= 134) atomicAdd(&cbig, 1);
  }
  for (int i = tid; i < 512; i += 256){
    if (ei32[2*i + 1] != 0) atomicAdd(&codd, 1);
  }
  __syncthreads();
  if (tid == 0){
    flags[0] = (cbig >= 64) ? 1 : 0;   // 1 -> floats are f32
    flags[1] = (codd < 8)  ? 1 : 0;    // 1 -> ints are int64
  }
}

// all 10 parameter tensors -> pf (f32) in one launch
struct PtrPack { const void* p[10]; };
__global__ void k_cvt_params(PtrPack pk, float* __restrict__ pf,
                             const int* __restrict__ flags){
  const int sz[10]  = {16384,16384,16384,16384,128,128,128,128,256,1};
  const int dst[10] = {0,16384,32768,49152,65536,65664,65792,65920,66048,66304};
  int i = blockIdx.x*blockDim.x + threadIdx.x;
  if (i >= 66305) return;
  int seg = 0, rem = i;
  while (rem >= sz[seg]){ rem -= sz[seg]; seg++; }
  pf[dst[seg] + rem] = rdf(pk.p[seg], rem, flags[0]);
}

__global__ void k_node_init(float* deg, unsigned* cnt, int N){
  int i = blockIdx.x*blockDim.x + threadIdx.x;
  if (i < N){ deg[i] = SELF_W; cnt[i] = 0u; }
}

// fused edge pass 1: deg/cnt atomics from raw inputs + esrc/ecoef prefill
__global__ void k_edge_deg(const void* __restrict__ ei, const void* __restrict__ ew,
                           float* __restrict__ deg, unsigned* __restrict__ cnt,
                           int* __restrict__ esrc, float* __restrict__ ecoef,
                           int E, int N, const int* __restrict__ flags){
  int e = blockIdx.x*blockDim.x + threadIdx.x;
  if (e >= E) return;
  esrc[e] = 0; ecoef[e] = 0.f;
  int d = rdi(ei, (long long)E + e, flags[1]);
  if ((unsigned)d < (unsigned)N){
    atomicAdd(&deg[d], rdf(ew, e, flags[0]));
    atomicAdd(&cnt[d], 1u);
  }
}

__global__ void k_dinv(float* deg, int N){
  int i = blockIdx.x*blockDim.x + threadIdx.x;
  if (i < N){ float d = deg[i]; deg[i] = (d > 0.f) ? rsqrtf(d) : 0.f; }
}

__device__ __forceinline__ unsigned wave_incl_scan(unsigned v){
  int lane = threadIdx.x & 63;
  #pragma unroll
  for (int d = 1; d < 64; d <<= 1){
    unsigned t = __shfl_up(v, d, 64);
    if (lane >= d) v += t;
  }
  return v;
}

// single-block exclusive scan of cnt -> off (shfl-based; resets cnt to 0)
__global__ __launch_bounds__(1024) void k_scan(unsigned* __restrict__ cnt,
                                               unsigned* __restrict__ off, int N){
  __shared__ unsigned wsum[16];
  __shared__ unsigned chunk_tot;
  int tid = threadIdx.x, lane = tid & 63, wid = tid >> 6;
  unsigned running = 0u;
  for (int base = 0; base < N; base += 4096){
    int i0 = base + tid*4;
    unsigned v0=0u,v1=0u,v2=0u,v3=0u;
    if (i0+0 < N){ v0 = cnt[i0+0]; cnt[i0+0] = 0u; }
    if (i0+1 < N){ v1 = cnt[i0+1]; cnt[i0+1] = 0u; }
    if (i0+2 < N){ v2 = cnt[i0+2]; cnt[i0+2] = 0u; }
    if (i0+3 < N){ v3 = cnt[i0+3]; cnt[i0+3] = 0u; }
    unsigned tsum = v0+v1+v2+v3;
    unsigned isc = wave_incl_scan(tsum);
    if (lane == 63) wsum[wid] = isc;
    __syncthreads();
    if (wid == 0){
      unsigned w = (lane < 16) ? wsum[lane] : 0u;
      unsigned wsc = wave_incl_scan(w);
      if (lane < 16) wsum[lane] = wsc - w;
      if (lane == 15) chunk_tot = wsc;
    }
    __syncthreads();
    unsigned ex = running + wsum[wid] + (isc - tsum);
    if (i0+0 < N) off[i0+0] = ex;
    if (i0+1 < N) off[i0+1] = ex + v0;
    if (i0+2 < N) off[i0+2] = ex + v0 + v1;
    if (i0+3 < N) off[i0+3] = ex + v0 + v1 + v2;
    running += chunk_tot;
    __syncthreads();
  }
  if (tid == 0) off[N] = running;
}

// edge pass 2: CSR scatter from raw inputs
__global__ void k_bucket(const void* __restrict__ ei, const void* __restrict__ ew,
                         const float* __restrict__ dinv,
                         const unsigned* __restrict__ off, unsigned* __restrict__ cur,
                         int* __restrict__ esrc, float* __restrict__ ecoef,
                         int E, int N, const int* __restrict__ flags){
  int e = blockIdx.x*blockDim.x + threadIdx.x;
  if (e >= E) return;
  int s_ = rdi(ei, e, flags[1]);
  int d  = rdi(ei, (long long)E + e, flags[1]);
  if ((unsigned)s_ >= (unsigned)N || (unsigned)d >= (unsigned)N) return;
  unsigned pos = off[d] + atomicAdd(&cur[d], 1u);
  if (pos < (unsigned)E){
    esrc[pos]  = s_;
    ecoef[pos] = dinv[s_] * rdf(ew, e, flags[0]) * dinv[d];
  }
}

// graph segment boundaries via binary search on raw sorted batch
__global__ void k_bounds(const void* __restrict__ bat, int N,
                         unsigned* __restrict__ start, unsigned* __restrict__ gcnt,
                         const int* __restrict__ flags){
  __shared__ unsigned s[NGRAPH+1];
  int g = threadIdx.x;
  int i64 = flags[1];
  if (g <= NGRAPH){
    int lo = 0, hi = N;
    while (lo < hi){ int mid = (lo + hi) >> 1; if (rdi(bat, mid, i64) < g) lo = mid + 1; else hi = mid; }
    s[g] = (unsigned)lo;
  }
  __syncthreads();
  if (g < NGRAPH){ start[g] = s[g]; gcnt[g] = s[g+1] - s[g]; }
  if (g == NGRAPH) start[NGRAPH] = s[NGRAPH];
}

// t[N,128] = in[N,128] @ W[128,128]; f32 math, fp16 output.
// MODE 0: in = raw x (flag-aware). MODE 1: in = f32 h.
template<int MODE>
__global__ __launch_bounds__(256) void k_gemm(const void* __restrict__ in,
                                              const float* __restrict__ W,
                                              __half* __restrict__ outh, int N,
                                              const int* __restrict__ flags){
  __shared__ float shA[128*68];
  int t = threadIdx.x;
  int row0 = blockIdx.x * 64;
  int f32 = (MODE == 0) ? flags[0] : 1;
  #pragma unroll
  for (int i = 0; i < 32; i++){
    int e = t + 256*i;
    int r = e >> 7, k = e & 127;
    int row = row0 + r;
    float v = 0.f;
    if (row < N){
      long long idx = (long long)row*FDIM + k;
      v = (MODE == 1) ? ((const float*)in)[idx] : rdf(in, idx, f32);
    }
    shA[k*68 + r] = v;
  }
  __syncthreads();

  int tcg = t & 15, trg = t >> 4;
  int r0 = trg * 4, j0 = tcg * 8;
  float acc[4][8];
  #pragma unroll
  for (int a_ = 0; a_ < 4; a_++)
    #pragma unroll
    for (int b_ = 0; b_ < 8; b_++) acc[a_][b_] = 0.f;

  #pragma unroll 4
  for (int k = 0; k < FDIM; k++){
    const float4 a  = *(const float4*)&shA[k*68 + r0];
    const float4* wr = (const float4*)(W + (size_t)k*FDIM + j0);
    const float4 w0 = wr[0];
    const float4 w1 = wr[1];
    const float av[4] = {a.x, a.y, a.z, a.w};
    const float wv[8] = {w0.x,w0.y,w0.z,w0.w, w1.x,w1.y,w1.z,w1.w};
    #pragma unroll
    for (int rr = 0; rr < 4; rr++)
      #pragma unroll
      for (int cc = 0; cc < 8; cc++)
        acc[rr][cc] += av[rr] * wv[cc];
  }

  #pragma unroll
  for (int rr = 0; rr < 4; rr++){
    int row = row0 + r0 + rr;
    if (row < N){
      float4 pack;
      __half2* hp = (__half2*)&pack;
      hp[0] = __floats2half2_rn(acc[rr][0], acc[rr][1]);
      hp[1] = __floats2half2_rn(acc[rr][2], acc[rr][3]);
      hp[2] = __floats2half2_rn(acc[rr][4], acc[rr][5]);
      hp[3] = __floats2half2_rn(acc[rr][6], acc[rr][7]);
      *(float4*)(outh + (size_t)row*FDIM + j0) = pack;
    }
  }
}

// one wave64 per node; lane owns 2 cols (one __half2). CSR gather, f32 accum,
// fused bias+tanh, f32 h output. Unroll x4 for MLP.
__global__ __launch_bounds__(256) void k_agg(const __half* __restrict__ th,
                                             const float* __restrict__ dinv,
                                             const unsigned* __restrict__ off,
                                             const int* __restrict__ esrc,
                                             const float* __restrict__ ecoef,
                                             const float* __restrict__ bias,
                                             float* __restrict__ hout, int N, int E){
  int n    = (int)((blockIdx.x*blockDim.x + threadIdx.x) >> 6);
  int lane = threadIdx.x & 63;
  if (n >= N) return;
  const __half2* t2 = (const __half2*)th;
  float di = dinv[n];
  float sw = di * di * SELF_W;
  float2 v = __half22float2(t2[(size_t)n*64 + lane]);
  float a0 = sw * v.x, a1 = sw * v.y;
  float b0 = 0.f, b1 = 0.f, c0 = 0.f, c1 = 0.f, d0 = 0.f, d1 = 0.f;
  unsigned beg = off[n], end = off[n+1];
  if (end > (unsigned)E) end = (unsigned)E;
  if (beg > end) beg = end;
  unsigned i = beg;
  for (; i + 4 <= end; i += 4){
    int  s0 = esrc[i],   s1 = esrc[i+1], s2 = esrc[i+2], s3 = esrc[i+3];
    float w0 = ecoef[i], w1 = ecoef[i+1], w2 = ecoef[i+2], w3 = ecoef[i+3];
    float2 t0 = __half22float2(t2[(size_t)s0*64 + lane]);
    float2 t1 = __half22float2(t2[(size_t)s1*64 + lane]);
    float2 t2v = __half22float2(t2[(size_t)s2*64 + lane]);
    float2 t3 = __half22float2(t2[(size_t)s3*64 + lane]);
    a0 += w0 * t0.x; a1 += w0 * t0.y;
    b0 += w1 * t1.x; b1 += w1 * t1.y;
    c0 += w2 * t2v.x; c1 += w2 * t2v.y;
    d0 += w3 * t3.x; d1 += w3 * t3.y;
  }
  for (; i < end; i++){
    int s_ = esrc[i];
    float cf = ecoef[i];
    float2 tv = __half22float2(t2[(size_t)s_*64 + lane]);
    a0 += cf * tv.x; a1 += cf * tv.y;
  }
  a0 += b0 + c0 + d0;
  a1 += b1 + c1 + d1;
  int cc = lane * 2;
  a0 = tanhf(a0 + bias[cc]);
  a1 = tanhf(a1 + bias[cc+1]);
  ((float2*)(hout + (size_t)n*FDIM))[lane] = make_float2(a0, a1);
}

__global__ void k_pool_init(unsigned* gmaxu, float* gsum){
  int i = blockIdx.x*blockDim.x + threadIdx.x;
  if (i < NGRAPH*FDIM){ gmaxu[i] = 0u; gsum[i] = 0.f; }
}

// 4 blocks per graph, contiguous node slices, register-local reduce, 1 atomic/col/block
__global__ __launch_bounds__(256) void k_pool2(const float* __restrict__ h,
                                               const unsigned* __restrict__ start,
                                               unsigned* __restrict__ gmaxu,
                                               float* __restrict__ gsum){
  int g = blockIdx.x >> 2, sub = blockIdx.x & 3;
  int col = threadIdx.x & 127, half = threadIdx.x >> 7;
  unsigned s0 = start[g], s1 = start[g+1];
  float m = -INFINITY, sm = 0.f;
  for (unsigned n = s0 + sub*2 + half; n < s1; n += 8){
    float v = h[(size_t)n*FDIM + col];
    m = fmaxf(m, v); sm += v;
  }
  __shared__ float shm[256], shs[256];
  shm[threadIdx.x] = m; shs[threadIdx.x] = sm;
  __syncthreads();
  if (half == 0){
    m = fmaxf(m, shm[threadIdx.x + 128]);
    sm += shs[threadIdx.x + 128];
    if (m > -INFINITY) atomicMax(&gmaxu[g*FDIM + col], fenc(m));
    atomicAdd(&gsum[g*FDIM + col], sm);
  }
}

// 64 blocks x 256 thr: hidden = [gmax | gmean], out = hidden @ Wout + bout
__global__ __launch_bounds__(256) void k_out(const unsigned* __restrict__ gmaxu,
                                             const float* __restrict__ gsum,
                                             const unsigned* __restrict__ gcnt,
                                             const float* __restrict__ Wout,
                                             const float* __restrict__ bout,
                                             void* __restrict__ outp,
                                             const int* __restrict__ flags){
  int g = blockIdx.x;
  int c = threadIdx.x;
  unsigned nc = gcnt[g];
  float val;
  if (c < FDIM){
    val = nc ? fdec(gmaxu[g*FDIM + c]) : 0.f;
  } else {
    float denom = nc ? (float)nc : 1.f;
    val = gsum[g*FDIM + (c - FDIM)] / denom;
  }
  int f32out = flags[0];
  int hidx = NGRAPH + g*(2*FDIM) + c;
  if (f32out) ((float*)outp)[hidx] = val;
  else        ((bf16*)outp)[hidx] = __float2bfloat16(val);

  __shared__ float red[256];
  red[c] = val * Wout[c];
  __syncthreads();
  for (int s = 128; s > 0; s >>= 1){
    if (c < s) red[c] += red[c + s];
    __syncthreads();
  }
  if (c == 0){
    float o = red[0] + bout[0];
    if (f32out) ((float*)outp)[g] = o;
    else        ((bf16*)outp)[g] = __float2bfloat16(o);
  }
}

extern "C" void kernel_launch(void* const* d_in, const int* in_sizes, int n_in,
                              void* d_out, int out_size, void* d_ws, size_t ws_size,
                              hipStream_t stream){
  int N = in_sizes[0] / FDIM;   // x: [N,128]
  int E = in_sizes[3];          // edge_weight: [E]

  char* p = (char*)d_ws;
  auto alloc = [&](size_t bytes){ char* r = p; p += (bytes + 255) & ~(size_t)255; return r; };
  int*      flags  = (int*)     alloc(16);
  float*    pf     = (float*)   alloc((size_t)(66305 + 64)*4);
  float*    deg    = (float*)   alloc((size_t)N*4);       // becomes dinv in place
  unsigned* cnt    = (unsigned*)alloc((size_t)N*4);
  unsigned* off    = (unsigned*)alloc((size_t)(N+1)*4);
  int*      esrc   = (int*)     alloc((size_t)E*4);
  float*    ecoef  = (float*)   alloc((size_t)E*4);
  __half*   th     = (__half*)  alloc((size_t)N*FDIM*2);  // fp16 transformed features
  float*    hbuf   = (float*)   alloc((size_t)N*FDIM*4);  // f32 activations
  unsigned* gmaxu  = (unsigned*)alloc((size_t)NGRAPH*FDIM*4);
  float*    gsum   = (float*)   alloc((size_t)NGRAPH*FDIM*4);
  unsigned* gcnt   = (unsigned*)alloc((size_t)NGRAPH*4);
  unsigned* gstart = (unsigned*)alloc((size_t)(NGRAPH+1)*4);

  float* Wf[4]  = {pf, pf + 16384, pf + 32768, pf + 49152};
  float* bf_[4] = {pf + 65536, pf + 65664, pf + 65792, pf + 65920};
  float* Woutf  = pf + 66048;
  float* boutf  = pf + 66304;

  k_probe<<<1, 256, 0, stream>>>((const unsigned short*)d_in[0], (const int*)d_in[1], flags);

  int gE = (E + 255)/256, gN = (N + 255)/256;
  PtrPack pk;
  pk.p[0]=d_in[4]; pk.p[1]=d_in[6]; pk.p[2]=d_in[8]; pk.p[3]=d_in[10];
  pk.p[4]=d_in[5]; pk.p[5]=d_in[7]; pk.p[6]=d_in[9]; pk.p[7]=d_in[11];
  pk.p[8]=d_in[12]; pk.p[9]=d_in[13];
  k_cvt_params<<<(66305 + 255)/256, 256, 0, stream>>>(pk, pf, flags);
  k_node_init<<<gN, 256, 0, stream>>>(deg, cnt, N);
  k_edge_deg<<<gE, 256, 0, stream>>>(d_in[1], d_in[3], deg, cnt, esrc, ecoef, E, N, flags);
  k_dinv<<<gN, 256, 0, stream>>>(deg, N);
  k_scan<<<1, 1024, 0, stream>>>(cnt, off, N);
  k_bucket<<<gE, 256, 0, stream>>>(d_in[1], d_in[3], deg, off, cnt, esrc, ecoef, E, N, flags);
  k_bounds<<<1, 128, 0, stream>>>(d_in[2], N, gstart, gcnt, flags);

  int gG = (N + 63)/64;
  int gA = (N + 3)/4;

  k_gemm<0><<<gG, 256, 0, stream>>>(d_in[0], Wf[0], th, N, flags);
  k_agg<<<gA, 256, 0, stream>>>(th, deg, off, esrc, ecoef, bf_[0], hbuf, N, E);
  for (int l = 1; l < 4; l++){
    k_gemm<1><<<gG, 256, 0, stream>>>(hbuf, Wf[l], th, N, flags);
    k_agg<<<gA, 256, 0, stream>>>(th, deg, off, esrc, ecoef, bf_[l], hbuf, N, E);
  }

  k_pool_init<<<(NGRAPH*FDIM + 255)/256, 256, 0, stream>>>(gmaxu, gsum);
  k_pool2<<<4*NGRAPH, 256, 0, stream>>>(hbuf, gstart, gmaxu, gsum);
  k_out<<<NGRAPH, 256, 0, stream>>>(gmaxu, gsum, gcnt, Woutf, boutf, d_out, flags);
}

// Round 5
// 473.040 us; speedup vs baseline: 2.4472x; 1.2451x over previous
//
#include <hip/hip_runtime.h>
#include <hip/hip_bf16.h>
#include <hip/hip_fp16.h>

typedef __hip_bfloat16 bf16;
typedef _Float16 half8 __attribute__((ext_vector_type(8)));
typedef float f32x4 __attribute__((ext_vector_type(4)));

#define FDIM 128
#define SELF_W 2.0f
#define NGRAPH 64
#define DEG_SCALE 1048576.0f          // 2^20 fixed point for weighted degree
#define DEG_MASK  ((1ull<<44) - 1ull) // low 44 bits = degree sum, high 20 = count

__device__ __forceinline__ float b2f(bf16 v){ return __bfloat162float(v); }

__device__ __forceinline__ unsigned fenc(float f){
  unsigned b = __float_as_uint(f);
  return (b & 0x80000000u) ? ~b : (b | 0x80000000u);
}
__device__ __forceinline__ float fdec(unsigned u){
  unsigned b = (u & 0x80000000u) ? (u ^ 0x80000000u) : ~u;
  return __uint_as_float(b);
}

__device__ __forceinline__ float rdf(const void* p, long long i, int f32){
  return f32 ? ((const float*)p)[i] : b2f(((const bf16*)p)[i]);
}
__device__ __forceinline__ int rdi(const void* p, long long i, int i64){
  return i64 ? (int)(((const long long*)p)[i]) : ((const int*)p)[i];
}

// ---- input-format probe: flags[0]=floats are f32, flags[1]=ints are int64 ----
__global__ __launch_bounds__(256) void k_probe(const unsigned short* __restrict__ x16,
                                               const int* __restrict__ ei32,
                                               int* __restrict__ flags){
  __shared__ int cbig, codd;
  int tid = threadIdx.x;
  if (tid == 0){ cbig = 0; codd = 0; }
  __syncthreads();
  for (int i = tid; i < 4096; i += 256){
    int e = (x16[i] >> 7) & 0xFF;
    if (e >= 134) atomicAdd(&cbig, 1);
  }
  for (int i = tid; i < 512; i += 256){
    if (ei32[2*i + 1] != 0) atomicAdd(&codd, 1);
  }
  __syncthreads();
  if (tid == 0){
    flags[0] = (cbig >= 64) ? 1 : 0;
    flags[1] = (codd < 8)  ? 1 : 0;
  }
}

// params -> pf (f32) AND WT fp16 transposed copies for MFMA B-operands
struct PtrPack { const void* p[10]; };
__global__ void k_cvt_params(PtrPack pk, float* __restrict__ pf,
                             _Float16* __restrict__ wt,
                             const int* __restrict__ flags){
  const int sz[10]  = {16384,16384,16384,16384,128,128,128,128,256,1};
  const int dst[10] = {0,16384,32768,49152,65536,65664,65792,65920,66048,66304};
  int i = blockIdx.x*blockDim.x + threadIdx.x;
  if (i >= 66305) return;
  int seg = 0, rem = i;
  while (rem >= sz[seg]){ rem -= sz[seg]; seg++; }
  float v = rdf(pk.p[seg], rem, flags[0]);
  pf[dst[seg] + rem] = v;
  if (seg < 4){                       // W[l][k][n] -> WT[l][n][k] fp16
    int k = rem >> 7, n = rem & 127;
    wt[seg*16384 + n*128 + k] = (_Float16)v;
  }
}

__global__ void k_packed_init(unsigned long long* packed, int N){
  int i = blockIdx.x*blockDim.x + threadIdx.x;
  if (i < N) packed[i] = (unsigned long long)(SELF_W * DEG_SCALE);
}

// edge pass 1: single u64 atomic = {count:20 | deg_fixed:44}; returned old
// value gives this edge's rank inside its dst bucket. epk prefilled.
__global__ void k_edge_deg(const void* __restrict__ ei, const void* __restrict__ ew,
                           unsigned long long* __restrict__ packed,
                           unsigned* __restrict__ rank, int2* __restrict__ epk,
                           int E, int N, const int* __restrict__ flags){
  int e = blockIdx.x*blockDim.x + threadIdx.x;
  if (e >= E) return;
  epk[e] = make_int2(0, 0);
  int d = rdi(ei, (long long)E + e, flags[1]);
  unsigned r = 0u;
  if ((unsigned)d < (unsigned)N){
    float w = rdf(ew, e, flags[0]);
    unsigned long long add = (1ull << 44) |
        (unsigned long long)__float2uint_rn(w * DEG_SCALE);
    unsigned long long old = atomicAdd(&packed[d], add);
    r = (unsigned)(old >> 44);
  }
  rank[e] = r;
}

__global__ void k_dinv(const unsigned long long* __restrict__ packed,
                       float* __restrict__ dinv, int N){
  int i = blockIdx.x*blockDim.x + threadIdx.x;
  if (i < N){
    float d = (float)(packed[i] & DEG_MASK) * (1.0f / DEG_SCALE);
    dinv[i] = (d > 0.f) ? rsqrtf(d) : 0.f;
  }
}

__device__ __forceinline__ unsigned wave_incl_scan(unsigned v){
  int lane = threadIdx.x & 63;
  #pragma unroll
  for (int d = 1; d < 64; d <<= 1){
    unsigned t = __shfl_up(v, d, 64);
    if (lane >= d) v += t;
  }
  return v;
}

// single-block exclusive scan of counts (high 20 bits of packed) -> off
__global__ __launch_bounds__(1024) void k_scan(const unsigned long long* __restrict__ packed,
                                               unsigned* __restrict__ off, int N){
  __shared__ unsigned wsum[16];
  __shared__ unsigned chunk_tot;
  int tid = threadIdx.x, lane = tid & 63, wid = tid >> 6;
  unsigned running = 0u;
  for (int base = 0; base < N; base += 4096){
    int i0 = base + tid*4;
    unsigned v0=0u,v1=0u,v2=0u,v3=0u;
    if (i0+0 < N) v0 = (unsigned)(packed[i0+0] >> 44);
    if (i0+1 < N) v1 = (unsigned)(packed[i0+1] >> 44);
    if (i0+2 < N) v2 = (unsigned)(packed[i0+2] >> 44);
    if (i0+3 < N) v3 = (unsigned)(packed[i0+3] >> 44);
    unsigned tsum = v0+v1+v2+v3;
    unsigned isc = wave_incl_scan(tsum);
    if (lane == 63) wsum[wid] = isc;
    __syncthreads();
    if (wid == 0){
      unsigned w = (lane < 16) ? wsum[lane] : 0u;
      unsigned wsc = wave_incl_scan(w);
      if (lane < 16) wsum[lane] = wsc - w;
      if (lane == 15) chunk_tot = wsc;
    }
    __syncthreads();
    unsigned ex = running + wsum[wid] + (isc - tsum);
    if (i0+0 < N) off[i0+0] = ex;
    if (i0+1 < N) off[i0+1] = ex + v0;
    if (i0+2 < N) off[i0+2] = ex + v0 + v1;
    if (i0+3 < N) off[i0+3] = ex + v0 + v1 + v2;
    running += chunk_tot;
    __syncthreads();
  }
  if (tid == 0) off[N] = running;
}

// edge pass 2: ATOMIC-FREE scatter using precomputed rank
__global__ void k_bucket(const void* __restrict__ ei, const void* __restrict__ ew,
                         const float* __restrict__ dinv,
                         const unsigned* __restrict__ off,
                         const unsigned* __restrict__ rank,
                         int2* __restrict__ epk,
                         int E, int N, const int* __restrict__ flags){
  int e = blockIdx.x*blockDim.x + threadIdx.x;
  if (e >= E) return;
  int s_ = rdi(ei, e, flags[1]);
  int d  = rdi(ei, (long long)E + e, flags[1]);
  if ((unsigned)s_ >= (unsigned)N || (unsigned)d >= (unsigned)N) return;
  unsigned pos = off[d] + rank[e];
  if (pos < (unsigned)E){
    float coef = dinv[s_] * rdf(ew, e, flags[0]) * dinv[d];
    epk[pos] = make_int2(s_, __float_as_int(coef));
  }
}

// graph segment boundaries via binary search on raw sorted batch
__global__ void k_bounds(const void* __restrict__ bat, int N,
                         unsigned* __restrict__ start, unsigned* __restrict__ gcnt,
                         const int* __restrict__ flags){
  __shared__ unsigned s[NGRAPH+1];
  int g = threadIdx.x;
  int i64 = flags[1];
  if (g <= NGRAPH){
    int lo = 0, hi = N;
    while (lo < hi){ int mid = (lo + hi) >> 1; if (rdi(bat, mid, i64) < g) lo = mid + 1; else hi = mid; }
    s[g] = (unsigned)lo;
  }
  __syncthreads();
  if (g < NGRAPH){ start[g] = s[g]; gcnt[g] = s[g+1] - s[g]; }
  if (g == NGRAPH) start[NGRAPH] = s[NGRAPH];
}

// MFMA GEMM: t[N,128](fp16) = in[N,128] @ W[128,128]
// block = 64 rows, 4 waves x 16 rows; v_mfma_f32_16x16x32_f16.
// A frags straight from global; B frags from WT (fp16, L1-resident).
// LDS only as output coalescing bounce.
// MODE 0: in = raw x (flag-aware f32/bf16). MODE 1: in = fp16 h.
template<int MODE>
__global__ __launch_bounds__(256) void k_gemm(const void* __restrict__ in,
                                              const _Float16* __restrict__ WT,
                                              __half* __restrict__ outh, int N,
                                              const int* __restrict__ flags){
  __shared__ _Float16 sout[4*16*136];   // [wave][16 rows][128+8 cols]
  int tid  = threadIdx.x;
  int wid  = tid >> 6, lane = tid & 63;
  int ln   = lane & 15, quad = lane >> 4;
  int row0 = blockIdx.x * 64;
  int rowA = row0 + wid*16 + ln;
  int rA   = (rowA < N) ? rowA : (N > 0 ? N-1 : 0);   // clamp; extra rows discarded

  half8 af[4];
  if (MODE == 1){
    const _Float16* src = (const _Float16*)in + (size_t)rA*FDIM + quad*8;
    #pragma unroll
    for (int kc = 0; kc < 4; kc++) af[kc] = *(const half8*)(src + kc*32);
  } else {
    if (flags[0]){
      const float* src = (const float*)in + (size_t)rA*FDIM + quad*8;
      #pragma unroll
      for (int kc = 0; kc < 4; kc++){
        float4 a = *(const float4*)(src + kc*32);
        float4 b = *(const float4*)(src + kc*32 + 4);
        half8 h; h[0]=(_Float16)a.x; h[1]=(_Float16)a.y; h[2]=(_Float16)a.z; h[3]=(_Float16)a.w;
        h[4]=(_Float16)b.x; h[5]=(_Float16)b.y; h[6]=(_Float16)b.z; h[7]=(_Float16)b.w;
        af[kc] = h;
      }
    } else {
      const unsigned short* src = (const unsigned short*)in + (size_t)rA*FDIM + quad*8;
      #pragma unroll
      for (int kc = 0; kc < 4; kc++){
        ushort4 u0 = *(const ushort4*)(src + kc*32);
        ushort4 u1 = *(const ushort4*)(src + kc*32 + 4);
        half8 h;
        h[0]=(_Float16)__uint_as_float((unsigned)u0.x<<16);
        h[1]=(_Float16)__uint_as_float((unsigned)u0.y<<16);
        h[2]=(_Float16)__uint_as_float((unsigned)u0.z<<16);
        h[3]=(_Float16)__uint_as_float((unsigned)u0.w<<16);
        h[4]=(_Float16)__uint_as_float((unsigned)u1.x<<16);
        h[5]=(_Float16)__uint_as_float((unsigned)u1.y<<16);
        h[6]=(_Float16)__uint_as_float((unsigned)u1.z<<16);
        h[7]=(_Float16)__uint_as_float((unsigned)u1.w<<16);
        af[kc] = h;
      }
    }
  }

  f32x4 acc[8];
  #pragma unroll
  for (int nt = 0; nt < 8; nt++) acc[nt] = (f32x4){0.f,0.f,0.f,0.f};

  #pragma unroll
  for (int kc = 0; kc < 4; kc++){
    #pragma unroll
    for (int nt = 0; nt < 8; nt++){
      half8 bf = *(const half8*)(WT + (size_t)(nt*16 + ln)*FDIM + kc*32 + quad*8);
      acc[nt] = __builtin_amdgcn_mfma_f32_16x16x32_f16(af[kc], bf, acc[nt], 0, 0, 0);
    }
  }

  // C layout: col = ln, row = quad*4 + reg  -> bounce through LDS, coalesced store
  _Float16* so = sout + wid*2176;
  #pragma unroll
  for (int nt = 0; nt < 8; nt++)
    #pragma unroll
    for (int reg = 0; reg < 4; reg++)
      so[(quad*4 + reg)*136 + nt*16 + ln] = (_Float16)acc[nt][reg];
  __syncthreads();

  #pragma unroll
  for (int c = 0; c < 4; c++){
    int chunk = tid + c*256;            // 1024 chunks of 8 fp16
    int r = chunk >> 4, co = (chunk & 15)*8;
    int row = row0 + r;
    if (row < N){
      half8 v = *(const half8*)(sout + (r>>4)*2176 + (r&15)*136 + co);
      *(half8*)((_Float16*)outh + (size_t)row*FDIM + co) = v;
    }
  }
}

// one wave64 per node; lane owns 2 cols. CSR gather (fp16 rows), f32 accum,
// fused bias+tanh, fp16 h output.
__global__ __launch_bounds__(256) void k_agg(const __half* __restrict__ th,
                                             const float* __restrict__ dinv,
                                             const unsigned* __restrict__ off,
                                             const int2* __restrict__ epk,
                                             const float* __restrict__ bias,
                                             __half* __restrict__ hout, int N, int E){
  int n    = (int)((blockIdx.x*blockDim.x + threadIdx.x) >> 6);
  int lane = threadIdx.x & 63;
  if (n >= N) return;
  const __half2* t2 = (const __half2*)th;
  float di = dinv[n];
  float sw = di * di * SELF_W;
  float2 v = __half22float2(t2[(size_t)n*64 + lane]);
  float a0 = sw * v.x, a1 = sw * v.y;
  float b0 = 0.f, b1 = 0.f, c0 = 0.f, c1 = 0.f, d0 = 0.f, d1 = 0.f;
  unsigned beg = off[n], end = off[n+1];
  if (end > (unsigned)E) end = (unsigned)E;
  if (beg > end) beg = end;
  unsigned i = beg;
  for (; i + 4 <= end; i += 4){
    int2 e0 = epk[i], e1 = epk[i+1], e2 = epk[i+2], e3 = epk[i+3];
    float2 t0 = __half22float2(t2[(size_t)e0.x*64 + lane]);
    float2 t1 = __half22float2(t2[(size_t)e1.x*64 + lane]);
    float2 t2v = __half22float2(t2[(size_t)e2.x*64 + lane]);
    float2 t3 = __half22float2(t2[(size_t)e3.x*64 + lane]);
    float w0 = __int_as_float(e0.y), w1 = __int_as_float(e1.y);
    float w2 = __int_as_float(e2.y), w3 = __int_as_float(e3.y);
    a0 += w0 * t0.x; a1 += w0 * t0.y;
    b0 += w1 * t1.x; b1 += w1 * t1.y;
    c0 += w2 * t2v.x; c1 += w2 * t2v.y;
    d0 += w3 * t3.x; d1 += w3 * t3.y;
  }
  for (; i < end; i++){
    int2 e0 = epk[i];
    float cf = __int_as_float(e0.y);
    float2 tv = __half22float2(t2[(size_t)e0.x*64 + lane]);
    a0 += cf * tv.x; a1 += cf * tv.y;
  }
  a0 += b0 + c0 + d0;
  a1 += b1 + c1 + d1;
  int cc = lane * 2;
  a0 = tanhf(a0 + bias[cc]);
  a1 = tanhf(a1 + bias[cc+1]);
  ((__half2*)hout)[(size_t)n*64 + lane] = __floats2half2_rn(a0, a1);
}

__global__ void k_pool_init(unsigned* gmaxu, float* gsum){
  int i = blockIdx.x*blockDim.x + threadIdx.x;
  if (i < NGRAPH*FDIM){ gmaxu[i] = 0u; gsum[i] = 0.f; }
}

// 4 blocks per graph, contiguous node slices (fp16 h), 1 atomic/col/block
__global__ __launch_bounds__(256) void k_pool2(const __half* __restrict__ h,
                                               const unsigned* __restrict__ start,
                                               unsigned* __restrict__ gmaxu,
                                               float* __restrict__ gsum){
  int g = blockIdx.x >> 2, sub = blockIdx.x & 3;
  int col = threadIdx.x & 127, half_ = threadIdx.x >> 7;
  unsigned s0 = start[g], s1 = start[g+1];
  float m = -INFINITY, sm = 0.f;
  for (unsigned n = s0 + sub*2 + half_; n < s1; n += 8){
    float v = __half2float(h[(size_t)n*FDIM + col]);
    m = fmaxf(m, v); sm += v;
  }
  __shared__ float shm[256], shs[256];
  shm[threadIdx.x] = m; shs[threadIdx.x] = sm;
  __syncthreads();
  if (half_ == 0){
    m = fmaxf(m, shm[threadIdx.x + 128]);
    sm += shs[threadIdx.x + 128];
    if (m > -INFINITY) atomicMax(&gmaxu[g*FDIM + col], fenc(m));
    atomicAdd(&gsum[g*FDIM + col], sm);
  }
}

// 64 blocks x 256 thr: hidden = [gmax | gmean], out = hidden @ Wout + bout
__global__ __launch_bounds__(256) void k_out(const unsigned* __restrict__ gmaxu,
                                             const float* __restrict__ gsum,
                                             const unsigned* __restrict__ gcnt,
                                             const float* __restrict__ Wout,
                                             const float* __restrict__ bout,
                                             void* __restrict__ outp,
                                             const int* __restrict__ flags){
  int g = blockIdx.x;
  int c = threadIdx.x;
  unsigned nc = gcnt[g];
  float val;
  if (c < FDIM){
    val = nc ? fdec(gmaxu[g*FDIM + c]) : 0.f;
  } else {
    float denom = nc ? (float)nc : 1.f;
    val = gsum[g*FDIM + (c - FDIM)] / denom;
  }
  int f32out = flags[0];
  int hidx = NGRAPH + g*(2*FDIM) + c;
  if (f32out) ((float*)outp)[hidx] = val;
  else        ((bf16*)outp)[hidx] = __float2bfloat16(val);

  __shared__ float red[256];
  red[c] = val * Wout[c];
  __syncthreads();
  for (int s = 128; s > 0; s >>= 1){
    if (c < s) red[c] += red[c + s];
    __syncthreads();
  }
  if (c == 0){
    float o = red[0] + bout[0];
    if (f32out) ((float*)outp)[g] = o;
    else        ((bf16*)outp)[g] = __float2bfloat16(o);
  }
}

extern "C" void kernel_launch(void* const* d_in, const int* in_sizes, int n_in,
                              void* d_out, int out_size, void* d_ws, size_t ws_size,
                              hipStream_t stream){
  int N = in_sizes[0] / FDIM;   // x: [N,128]
  int E = in_sizes[3];          // edge_weight: [E]

  char* p = (char*)d_ws;
  auto alloc = [&](size_t bytes){ char* r = p; p += (bytes + 255) & ~(size_t)255; return r; };
  int*       flags  = (int*)      alloc(16);
  float*     pf     = (float*)    alloc((size_t)(66305 + 64)*4);
  _Float16*  wt     = (_Float16*) alloc((size_t)4*FDIM*FDIM*2);
  unsigned long long* packed = (unsigned long long*)alloc((size_t)N*8);
  float*     dinv   = (float*)    alloc((size_t)N*4);
  unsigned*  off    = (unsigned*) alloc((size_t)(N+1)*4);
  unsigned*  rank   = (unsigned*) alloc((size_t)E*4);
  int2*      epk    = (int2*)     alloc((size_t)E*8);
  __half*    th     = (__half*)   alloc((size_t)N*FDIM*2);  // fp16 transformed feats
  __half*    hh     = (__half*)   alloc((size_t)N*FDIM*2);  // fp16 activations
  unsigned*  gmaxu  = (unsigned*) alloc((size_t)NGRAPH*FDIM*4);
  float*     gsum   = (float*)    alloc((size_t)NGRAPH*FDIM*4);
  unsigned*  gcnt   = (unsigned*) alloc((size_t)NGRAPH*4);
  unsigned*  gstart = (unsigned*) alloc((size_t)(NGRAPH+1)*4);

  float* Wf[4]  = {pf, pf + 16384, pf + 32768, pf + 49152};  (void)Wf;
  float* bf_[4] = {pf + 65536, pf + 65664, pf + 65792, pf + 65920};
  float* Woutf  = pf + 66048;
  float* boutf  = pf + 66304;

  k_probe<<<1, 256, 0, stream>>>((const unsigned short*)d_in[0], (const int*)d_in[1], flags);

  int gE = (E + 255)/256, gN = (N + 255)/256;
  PtrPack pk;
  pk.p[0]=d_in[4]; pk.p[1]=d_in[6]; pk.p[2]=d_in[8]; pk.p[3]=d_in[10];
  pk.p[4]=d_in[5]; pk.p[5]=d_in[7]; pk.p[6]=d_in[9]; pk.p[7]=d_in[11];
  pk.p[8]=d_in[12]; pk.p[9]=d_in[13];
  k_cvt_params<<<(66305 + 255)/256, 256, 0, stream>>>(pk, pf, wt, flags);
  k_packed_init<<<gN, 256, 0, stream>>>(packed, N);
  k_edge_deg<<<gE, 256, 0, stream>>>(d_in[1], d_in[3], packed, rank, epk, E, N, flags);
  k_dinv<<<gN, 256, 0, stream>>>(packed, dinv, N);
  k_scan<<<1, 1024, 0, stream>>>(packed, off, N);
  k_bucket<<<gE, 256, 0, stream>>>(d_in[1], d_in[3], dinv, off, rank, epk, E, N, flags);
  k_bounds<<<1, 128, 0, stream>>>(d_in[2], N, gstart, gcnt, flags);

  int gG = (N + 63)/64;
  int gA = (N + 3)/4;

  k_gemm<0><<<gG, 256, 0, stream>>>(d_in[0], wt + 0*16384, th, N, flags);
  k_agg<<<gA, 256, 0, stream>>>(th, dinv, off, epk, bf_[0], hh, N, E);
  for (int l = 1; l < 4; l++){
    k_gemm<1><<<gG, 256, 0, stream>>>(hh, wt + (size_t)l*16384, th, N, flags);
    k_agg<<<gA, 256, 0, stream>>>(th, dinv, off, epk, bf_[l], hh, N, E);
  }

  k_pool_init<<<(NGRAPH*FDIM + 255)/256, 256, 0, stream>>>(gmaxu, gsum);
  k_pool2<<<4*NGRAPH, 256, 0, stream>>>(hh, gstart, gmaxu, gsum);
  k_out<<<NGRAPH, 256, 0, stream>>>(gmaxu, gsum, gcnt, Woutf, boutf, d_out, flags);
}

// Round 6
// 449.528 us; speedup vs baseline: 2.5752x; 1.0523x over previous
//
#include <hip/hip_runtime.h>
#include <hip/hip_bf16.h>
#include <hip/hip_fp16.h>

typedef __hip_bfloat16 bf16;
typedef _Float16 half8 __attribute__((ext_vector_type(8)));
typedef float f32x4 __attribute__((ext_vector_type(4)));

#define FDIM 128
#define SELF_W 2.0f
#define NGRAPH 64
#define DEG_SCALE 1048576.0f          // 2^20 fixed point for weighted degree
#define DEG_MASK  ((1ull<<44) - 1ull) // low 44 bits = degree sum, high 20 = count

__device__ __forceinline__ float b2f(bf16 v){ return __bfloat162float(v); }

__device__ __forceinline__ unsigned fenc(float f){
  unsigned b = __float_as_uint(f);
  return (b & 0x80000000u) ? ~b : (b | 0x80000000u);
}
__device__ __forceinline__ float fdec(unsigned u){
  unsigned b = (u & 0x80000000u) ? (u ^ 0x80000000u) : ~u;
  return __uint_as_float(b);
}

__device__ __forceinline__ float rdf(const void* p, long long i, int f32){
  return f32 ? ((const float*)p)[i] : b2f(((const bf16*)p)[i]);
}
__device__ __forceinline__ int rdi(const void* p, long long i, int i64){
  return i64 ? (int)(((const long long*)p)[i]) : ((const int*)p)[i];
}

// ---- input-format probe: flags[0]=floats are f32, flags[1]=ints are int64 ----
__global__ __launch_bounds__(256) void k_probe(const unsigned short* __restrict__ x16,
                                               const int* __restrict__ ei32,
                                               int* __restrict__ flags){
  __shared__ int cbig, codd;
  int tid = threadIdx.x;
  if (tid == 0){ cbig = 0; codd = 0; }
  __syncthreads();
  for (int i = tid; i < 4096; i += 256){
    int e = (x16[i] >> 7) & 0xFF;
    if (e >= 134) atomicAdd(&cbig, 1);
  }
  for (int i = tid; i < 512; i += 256){
    if (ei32[2*i + 1] != 0) atomicAdd(&codd, 1);
  }
  __syncthreads();
  if (tid == 0){
    flags[0] = (cbig >= 64) ? 1 : 0;
    flags[1] = (codd < 8)  ? 1 : 0;
  }
}

// params -> pf (f32) AND WT fp16 transposed copies for MFMA B-operands
struct PtrPack { const void* p[10]; };
__global__ void k_cvt_params(PtrPack pk, float* __restrict__ pf,
                             _Float16* __restrict__ wt,
                             const int* __restrict__ flags){
  const int sz[10]  = {16384,16384,16384,16384,128,128,128,128,256,1};
  const int dst[10] = {0,16384,32768,49152,65536,65664,65792,65920,66048,66304};
  int i = blockIdx.x*blockDim.x + threadIdx.x;
  if (i >= 66305) return;
  int seg = 0, rem = i;
  while (rem >= sz[seg]){ rem -= sz[seg]; seg++; }
  float v = rdf(pk.p[seg], rem, flags[0]);
  pf[dst[seg] + rem] = v;
  if (seg < 4){                       // W[l][k][n] -> WT[l][n][k] fp16
    int k = rem >> 7, n = rem & 127;
    wt[seg*16384 + n*128 + k] = (_Float16)v;
  }
}

__global__ void k_packed_init(unsigned long long* packed, int N){
  int i = blockIdx.x*blockDim.x + threadIdx.x;
  if (i < N) packed[i] = (unsigned long long)(SELF_W * DEG_SCALE);
}

// edge pass 1: single u64 atomic = {count:20 | deg_fixed:44}; returned old
// value gives this edge's rank inside its dst bucket. epk prefilled.
__global__ void k_edge_deg(const void* __restrict__ ei, const void* __restrict__ ew,
                           unsigned long long* __restrict__ packed,
                           unsigned* __restrict__ rank, int2* __restrict__ epk,
                           int E, int N, const int* __restrict__ flags){
  int e = blockIdx.x*blockDim.x + threadIdx.x;
  if (e >= E) return;
  epk[e] = make_int2(0, 0);
  int d = rdi(ei, (long long)E + e, flags[1]);
  unsigned r = 0u;
  if ((unsigned)d < (unsigned)N){
    float w = rdf(ew, e, flags[0]);
    unsigned long long add = (1ull << 44) |
        (unsigned long long)__float2uint_rn(w * DEG_SCALE);
    unsigned long long old = atomicAdd(&packed[d], add);
    r = (unsigned)(old >> 44);
  }
  rank[e] = r;
}

__device__ __forceinline__ unsigned wave_incl_scan(unsigned v){
  int lane = threadIdx.x & 63;
  #pragma unroll
  for (int d = 1; d < 64; d <<= 1){
    unsigned t = __shfl_up(v, d, 64);
    if (lane >= d) v += t;
  }
  return v;
}

// scan phase A: per-block (1024 nodes) count-sum -> bsum; fused dinv compute
__global__ __launch_bounds__(256) void k_scan_pre(const unsigned long long* __restrict__ packed,
                                                  float* __restrict__ dinv,
                                                  unsigned* __restrict__ bsum, int N){
  __shared__ unsigned wsh[4];
  int tid = threadIdx.x, lane = tid & 63, wid = tid >> 6;
  int i0 = blockIdx.x*1024 + tid*4;
  unsigned tsum = 0u;
  #pragma unroll
  for (int j = 0; j < 4; j++){
    int i = i0 + j;
    if (i < N){
      unsigned long long pv = packed[i];
      tsum += (unsigned)(pv >> 44);
      float d = (float)(pv & DEG_MASK) * (1.0f / DEG_SCALE);
      dinv[i] = (d > 0.f) ? rsqrtf(d) : 0.f;
    }
  }
  #pragma unroll
  for (int d = 1; d < 64; d <<= 1) tsum += __shfl_down(tsum, d, 64);
  if (lane == 0) wsh[wid] = tsum;
  __syncthreads();
  if (tid == 0) bsum[blockIdx.x] = wsh[0] + wsh[1] + wsh[2] + wsh[3];
}

// scan phase B: one wave scans block sums (nb <= 64) -> exclusive base; off[N]=total
__global__ __launch_bounds__(64) void k_scan_mid(unsigned* __restrict__ bsum,
                                                 unsigned* __restrict__ off,
                                                 int nb, int N){
  int lane = threadIdx.x;
  unsigned v = (lane < nb) ? bsum[lane] : 0u;
  unsigned isc = wave_incl_scan(v);
  if (lane < nb) bsum[lane] = isc - v;   // exclusive base per block
  if (lane == 63) off[N] = isc;
}

// scan phase C: per-block local exclusive scan + base -> off
__global__ __launch_bounds__(256) void k_scan_fin(const unsigned long long* __restrict__ packed,
                                                  const unsigned* __restrict__ bsum,
                                                  unsigned* __restrict__ off, int N){
  __shared__ unsigned wsh[4];
  int tid = threadIdx.x, lane = tid & 63, wid = tid >> 6;
  int i0 = blockIdx.x*1024 + tid*4;
  unsigned v0=0u,v1=0u,v2=0u,v3=0u;
  if (i0+0 < N) v0 = (unsigned)(packed[i0+0] >> 44);
  if (i0+1 < N) v1 = (unsigned)(packed[i0+1] >> 44);
  if (i0+2 < N) v2 = (unsigned)(packed[i0+2] >> 44);
  if (i0+3 < N) v3 = (unsigned)(packed[i0+3] >> 44);
  unsigned tsum = v0+v1+v2+v3;
  unsigned isc = wave_incl_scan(tsum);
  if (lane == 63) wsh[wid] = isc;
  __syncthreads();
  unsigned wbase = 0u;
  #pragma unroll
  for (int w = 0; w < 4; w++) if (w < wid) wbase += wsh[w];
  unsigned ex = bsum[blockIdx.x] + wbase + (isc - tsum);
  if (i0+0 < N) off[i0+0] = ex;
  if (i0+1 < N) off[i0+1] = ex + v0;
  if (i0+2 < N) off[i0+2] = ex + v0 + v1;
  if (i0+3 < N) off[i0+3] = ex + v0 + v1 + v2;
}

// edge pass 2: ATOMIC-FREE scatter using precomputed rank
__global__ void k_bucket(const void* __restrict__ ei, const void* __restrict__ ew,
                         const float* __restrict__ dinv,
                         const unsigned* __restrict__ off,
                         const unsigned* __restrict__ rank,
                         int2* __restrict__ epk,
                         int E, int N, const int* __restrict__ flags){
  int e = blockIdx.x*blockDim.x + threadIdx.x;
  if (e >= E) return;
  int s_ = rdi(ei, e, flags[1]);
  int d  = rdi(ei, (long long)E + e, flags[1]);
  if ((unsigned)s_ >= (unsigned)N || (unsigned)d >= (unsigned)N) return;
  unsigned pos = off[d] + rank[e];
  if (pos < (unsigned)E){
    float coef = dinv[s_] * rdf(ew, e, flags[0]) * dinv[d];
    epk[pos] = make_int2(s_, __float_as_int(coef));
  }
}

// graph segment boundaries via binary search on raw sorted batch
__global__ void k_bounds(const void* __restrict__ bat, int N,
                         unsigned* __restrict__ start, unsigned* __restrict__ gcnt,
                         const int* __restrict__ flags){
  __shared__ unsigned s[NGRAPH+1];
  int g = threadIdx.x;
  int i64 = flags[1];
  if (g <= NGRAPH){
    int lo = 0, hi = N;
    while (lo < hi){ int mid = (lo + hi) >> 1; if (rdi(bat, mid, i64) < g) lo = mid + 1; else hi = mid; }
    s[g] = (unsigned)lo;
  }
  __syncthreads();
  if (g < NGRAPH){ start[g] = s[g]; gcnt[g] = s[g+1] - s[g]; }
  if (g == NGRAPH) start[NGRAPH] = s[NGRAPH];
}

// MFMA GEMM: t[N,128](fp16) = in[N,128] @ W[128,128]
template<int MODE>
__global__ __launch_bounds__(256) void k_gemm(const void* __restrict__ in,
                                              const _Float16* __restrict__ WT,
                                              __half* __restrict__ outh, int N,
                                              const int* __restrict__ flags){
  __shared__ _Float16 sout[4*16*136];   // [wave][16 rows][128+8 cols]
  int tid  = threadIdx.x;
  int wid  = tid >> 6, lane = tid & 63;
  int ln   = lane & 15, quad = lane >> 4;
  int row0 = blockIdx.x * 64;
  int rowA = row0 + wid*16 + ln;
  int rA   = (rowA < N) ? rowA : (N > 0 ? N-1 : 0);

  half8 af[4];
  if (MODE == 1){
    const _Float16* src = (const _Float16*)in + (size_t)rA*FDIM + quad*8;
    #pragma unroll
    for (int kc = 0; kc < 4; kc++) af[kc] = *(const half8*)(src + kc*32);
  } else {
    if (flags[0]){
      const float* src = (const float*)in + (size_t)rA*FDIM + quad*8;
      #pragma unroll
      for (int kc = 0; kc < 4; kc++){
        float4 a = *(const float4*)(src + kc*32);
        float4 b = *(const float4*)(src + kc*32 + 4);
        half8 h; h[0]=(_Float16)a.x; h[1]=(_Float16)a.y; h[2]=(_Float16)a.z; h[3]=(_Float16)a.w;
        h[4]=(_Float16)b.x; h[5]=(_Float16)b.y; h[6]=(_Float16)b.z; h[7]=(_Float16)b.w;
        af[kc] = h;
      }
    } else {
      const unsigned short* src = (const unsigned short*)in + (size_t)rA*FDIM + quad*8;
      #pragma unroll
      for (int kc = 0; kc < 4; kc++){
        ushort4 u0 = *(const ushort4*)(src + kc*32);
        ushort4 u1 = *(const ushort4*)(src + kc*32 + 4);
        half8 h;
        h[0]=(_Float16)__uint_as_float((unsigned)u0.x<<16);
        h[1]=(_Float16)__uint_as_float((unsigned)u0.y<<16);
        h[2]=(_Float16)__uint_as_float((unsigned)u0.z<<16);
        h[3]=(_Float16)__uint_as_float((unsigned)u0.w<<16);
        h[4]=(_Float16)__uint_as_float((unsigned)u1.x<<16);
        h[5]=(_Float16)__uint_as_float((unsigned)u1.y<<16);
        h[6]=(_Float16)__uint_as_float((unsigned)u1.z<<16);
        h[7]=(_Float16)__uint_as_float((unsigned)u1.w<<16);
        af[kc] = h;
      }
    }
  }

  f32x4 acc[8];
  #pragma unroll
  for (int nt = 0; nt < 8; nt++) acc[nt] = (f32x4){0.f,0.f,0.f,0.f};

  #pragma unroll
  for (int kc = 0; kc < 4; kc++){
    #pragma unroll
    for (int nt = 0; nt < 8; nt++){
      half8 bf = *(const half8*)(WT + (size_t)(nt*16 + ln)*FDIM + kc*32 + quad*8);
      acc[nt] = __builtin_amdgcn_mfma_f32_16x16x32_f16(af[kc], bf, acc[nt], 0, 0, 0);
    }
  }

  _Float16* so = sout + wid*2176;
  #pragma unroll
  for (int nt = 0; nt < 8; nt++)
    #pragma unroll
    for (int reg = 0; reg < 4; reg++)
      so[(quad*4 + reg)*136 + nt*16 + ln] = (_Float16)acc[nt][reg];
  __syncthreads();

  #pragma unroll
  for (int c = 0; c < 4; c++){
    int chunk = tid + c*256;
    int r = chunk >> 4, co = (chunk & 15)*8;
    int row = row0 + r;
    if (row < N){
      half8 v = *(const half8*)(sout + (r>>4)*2176 + (r&15)*136 + co);
      *(half8*)((_Float16*)outh + (size_t)row*FDIM + co) = v;
    }
  }
}

// one wave64 per node; lane owns 2 cols. CSR gather (fp16 rows), f32 accum,
// fused bias+tanh, fp16 h output. Unroll x8 for gather-latency MLP.
__global__ __launch_bounds__(256) void k_agg(const __half* __restrict__ th,
                                             const float* __restrict__ dinv,
                                             const unsigned* __restrict__ off,
                                             const int2* __restrict__ epk,
                                             const float* __restrict__ bias,
                                             __half* __restrict__ hout, int N, int E){
  int n    = (int)((blockIdx.x*blockDim.x + threadIdx.x) >> 6);
  int lane = threadIdx.x & 63;
  if (n >= N) return;
  const __half2* t2 = (const __half2*)th;
  float di = dinv[n];
  float sw = di * di * SELF_W;
  float2 v = __half22float2(t2[(size_t)n*64 + lane]);
  float a0 = sw * v.x, a1 = sw * v.y;
  float b0 = 0.f, b1 = 0.f, c0 = 0.f, c1 = 0.f, d0 = 0.f, d1 = 0.f;
  unsigned beg = off[n], end = off[n+1];
  if (end > (unsigned)E) end = (unsigned)E;
  if (beg > end) beg = end;
  unsigned i = beg;
  for (; i + 8 <= end; i += 8){
    int2 e0 = epk[i],   e1 = epk[i+1], e2 = epk[i+2], e3 = epk[i+3];
    int2 e4 = epk[i+4], e5 = epk[i+5], e6 = epk[i+6], e7 = epk[i+7];
    float2 t0 = __half22float2(t2[(size_t)e0.x*64 + lane]);
    float2 t1 = __half22float2(t2[(size_t)e1.x*64 + lane]);
    float2 t2v= __half22float2(t2[(size_t)e2.x*64 + lane]);
    float2 t3 = __half22float2(t2[(size_t)e3.x*64 + lane]);
    float2 t4 = __half22float2(t2[(size_t)e4.x*64 + lane]);
    float2 t5 = __half22float2(t2[(size_t)e5.x*64 + lane]);
    float2 t6 = __half22float2(t2[(size_t)e6.x*64 + lane]);
    float2 t7 = __half22float2(t2[(size_t)e7.x*64 + lane]);
    float w0 = __int_as_float(e0.y), w1 = __int_as_float(e1.y);
    float w2 = __int_as_float(e2.y), w3 = __int_as_float(e3.y);
    float w4 = __int_as_float(e4.y), w5 = __int_as_float(e5.y);
    float w6 = __int_as_float(e6.y), w7 = __int_as_float(e7.y);
    a0 += w0 * t0.x; a1 += w0 * t0.y;
    b0 += w1 * t1.x; b1 += w1 * t1.y;
    c0 += w2 * t2v.x; c1 += w2 * t2v.y;
    d0 += w3 * t3.x; d1 += w3 * t3.y;
    a0 += w4 * t4.x; a1 += w4 * t4.y;
    b0 += w5 * t5.x; b1 += w5 * t5.y;
    c0 += w6 * t6.x; c1 += w6 * t6.y;
    d0 += w7 * t7.x; d1 += w7 * t7.y;
  }
  for (; i < end; i++){
    int2 e0 = epk[i];
    float cf = __int_as_float(e0.y);
    float2 tv = __half22float2(t2[(size_t)e0.x*64 + lane]);
    a0 += cf * tv.x; a1 += cf * tv.y;
  }
  a0 += b0 + c0 + d0;
  a1 += b1 + c1 + d1;
  int cc = lane * 2;
  a0 = tanhf(a0 + bias[cc]);
  a1 = tanhf(a1 + bias[cc+1]);
  ((__half2*)hout)[(size_t)n*64 + lane] = __floats2half2_rn(a0, a1);
}

__global__ void k_pool_init(unsigned* gmaxu, float* gsum){
  int i = blockIdx.x*blockDim.x + threadIdx.x;
  if (i < NGRAPH*FDIM){ gmaxu[i] = 0u; gsum[i] = 0.f; }
}

// 4 blocks per graph, contiguous node slices (fp16 h), 1 atomic/col/block
__global__ __launch_bounds__(256) void k_pool2(const __half* __restrict__ h,
                                               const unsigned* __restrict__ start,
                                               unsigned* __restrict__ gmaxu,
                                               float* __restrict__ gsum){
  int g = blockIdx.x >> 2, sub = blockIdx.x & 3;
  int col = threadIdx.x & 127, half_ = threadIdx.x >> 7;
  unsigned s0 = start[g], s1 = start[g+1];
  float m = -INFINITY, sm = 0.f;
  for (unsigned n = s0 + sub*2 + half_; n < s1; n += 8){
    float v = __half2float(h[(size_t)n*FDIM + col]);
    m = fmaxf(m, v); sm += v;
  }
  __shared__ float shm[256], shs[256];
  shm[threadIdx.x] = m; shs[threadIdx.x] = sm;
  __syncthreads();
  if (half_ == 0){
    m = fmaxf(m, shm[threadIdx.x + 128]);
    sm += shs[threadIdx.x + 128];
    if (m > -INFINITY) atomicMax(&gmaxu[g*FDIM + col], fenc(m));
    atomicAdd(&gsum[g*FDIM + col], sm);
  }
}

// 64 blocks x 256 thr: hidden = [gmax | gmean], out = hidden @ Wout + bout
__global__ __launch_bounds__(256) void k_out(const unsigned* __restrict__ gmaxu,
                                             const float* __restrict__ gsum,
                                             const unsigned* __restrict__ gcnt,
                                             const float* __restrict__ Wout,
                                             const float* __restrict__ bout,
                                             void* __restrict__ outp,
                                             const int* __restrict__ flags){
  int g = blockIdx.x;
  int c = threadIdx.x;
  unsigned nc = gcnt[g];
  float val;
  if (c < FDIM){
    val = nc ? fdec(gmaxu[g*FDIM + c]) : 0.f;
  } else {
    float denom = nc ? (float)nc : 1.f;
    val = gsum[g*FDIM + (c - FDIM)] / denom;
  }
  int f32out = flags[0];
  int hidx = NGRAPH + g*(2*FDIM) + c;
  if (f32out) ((float*)outp)[hidx] = val;
  else        ((bf16*)outp)[hidx] = __float2bfloat16(val);

  __shared__ float red[256];
  red[c] = val * Wout[c];
  __syncthreads();
  for (int s = 128; s > 0; s >>= 1){
    if (c < s) red[c] += red[c + s];
    __syncthreads();
  }
  if (c == 0){
    float o = red[0] + bout[0];
    if (f32out) ((float*)outp)[g] = o;
    else        ((bf16*)outp)[g] = __float2bfloat16(o);
  }
}

extern "C" void kernel_launch(void* const* d_in, const int* in_sizes, int n_in,
                              void* d_out, int out_size, void* d_ws, size_t ws_size,
                              hipStream_t stream){
  int N = in_sizes[0] / FDIM;   // x: [N,128]
  int E = in_sizes[3];          // edge_weight: [E]
  int NB = (N + 1023) / 1024;   // scan blocks (<=64 for N<=65536)

  char* p = (char*)d_ws;
  auto alloc = [&](size_t bytes){ char* r = p; p += (bytes + 255) & ~(size_t)255; return r; };
  int*       flags  = (int*)      alloc(16);
  float*     pf     = (float*)    alloc((size_t)(66305 + 64)*4);
  _Float16*  wt     = (_Float16*) alloc((size_t)4*FDIM*FDIM*2);
  unsigned long long* packed = (unsigned long long*)alloc((size_t)N*8);
  float*     dinv   = (float*)    alloc((size_t)N*4);
  unsigned*  off    = (unsigned*) alloc((size_t)(N+1)*4);
  unsigned*  bsum   = (unsigned*) alloc((size_t)128*4);
  unsigned*  rank   = (unsigned*) alloc((size_t)E*4);
  int2*      epk    = (int2*)     alloc((size_t)E*8);
  __half*    th     = (__half*)   alloc((size_t)N*FDIM*2);
  __half*    hh     = (__half*)   alloc((size_t)N*FDIM*2);
  unsigned*  gmaxu  = (unsigned*) alloc((size_t)NGRAPH*FDIM*4);
  float*     gsum   = (float*)    alloc((size_t)NGRAPH*FDIM*4);
  unsigned*  gcnt   = (unsigned*) alloc((size_t)NGRAPH*4);
  unsigned*  gstart = (unsigned*) alloc((size_t)(NGRAPH+1)*4);

  float* bf_[4] = {pf + 65536, pf + 65664, pf + 65792, pf + 65920};
  float* Woutf  = pf + 66048;
  float* boutf  = pf + 66304;

  k_probe<<<1, 256, 0, stream>>>((const unsigned short*)d_in[0], (const int*)d_in[1], flags);

  int gE = (E + 255)/256, gN = (N + 255)/256;
  PtrPack pk;
  pk.p[0]=d_in[4]; pk.p[1]=d_in[6]; pk.p[2]=d_in[8]; pk.p[3]=d_in[10];
  pk.p[4]=d_in[5]; pk.p[5]=d_in[7]; pk.p[6]=d_in[9]; pk.p[7]=d_in[11];
  pk.p[8]=d_in[12]; pk.p[9]=d_in[13];
  k_cvt_params<<<(66305 + 255)/256, 256, 0, stream>>>(pk, pf, wt, flags);
  k_packed_init<<<gN, 256, 0, stream>>>(packed, N);
  k_edge_deg<<<gE, 256, 0, stream>>>(d_in[1], d_in[3], packed, rank, epk, E, N, flags);
  k_scan_pre<<<NB, 256, 0, stream>>>(packed, dinv, bsum, N);
  k_scan_mid<<<1, 64, 0, stream>>>(bsum, off, NB, N);
  k_scan_fin<<<NB, 256, 0, stream>>>(packed, bsum, off, N);
  k_bucket<<<gE, 256, 0, stream>>>(d_in[1], d_in[3], dinv, off, rank, epk, E, N, flags);
  k_bounds<<<1, 128, 0, stream>>>(d_in[2], N, gstart, gcnt, flags);

  int gG = (N + 63)/64;
  int gA = (N + 3)/4;

  k_gemm<0><<<gG, 256, 0, stream>>>(d_in[0], wt + 0*16384, th, N, flags);
  k_agg<<<gA, 256, 0, stream>>>(th, dinv, off, epk, bf_[0], hh, N, E);
  for (int l = 1; l < 4; l++){
    k_gemm<1><<<gG, 256, 0, stream>>>(hh, wt + (size_t)l*16384, th, N, flags);
    k_agg<<<gA, 256, 0, stream>>>(th, dinv, off, epk, bf_[l], hh, N, E);
  }

  k_pool_init<<<(NGRAPH*FDIM + 255)/256, 256, 0, stream>>>(gmaxu, gsum);
  k_pool2<<<4*NGRAPH, 256, 0, stream>>>(hh, gstart, gmaxu, gsum);
  k_out<<<NGRAPH, 256, 0, stream>>>(gmaxu, gsum, gcnt, Woutf, boutf, d_out, flags);
}